// Round 9
// baseline (809.139 us; speedup 1.0000x reference)
//
#include <hip/hip_runtime.h>
#include <stdint.h>

typedef unsigned short u16;
typedef __attribute__((ext_vector_type(8))) short bf16x8;   // 8 bf16 = 4 VGPRs
typedef __attribute__((ext_vector_type(4))) float f32x4;

#define NUM_B 2
#define SEQ   2048
#define SEQP  2080      // padded V row stride
#define NH    16
#define HD    128
#define EMB   2048      // NH*HD
#define N3    6144      // 3*EMB
#define MM    4096      // NUM_B*SEQ
#define QT    64        // flash q-rows per block (2 waves)
#define WQ    32        // flash q-rows per wave
#define KT    32        // flash keys per k-tile
#define NTILE (SEQ / KT)

// ---- GEMM tile params: 256x384, BK=64, FAT-WAVE (4 waves, 1/SIMD, 512-reg budget) ----
#define BM 256
#define BN 384
#define BK 64
#define NT_K (EMB / BK)   // 32 K-tiles

__device__ __forceinline__ u16 f2bf(float f) {
  union { float f; unsigned u; } c; c.f = f;
  return (u16)((c.u + 0x7FFFu + ((c.u >> 16) & 1u)) >> 16);   // RNE
}
__device__ __forceinline__ void async16(const void* g, void* l) {
  __builtin_amdgcn_global_load_lds(
      (const __attribute__((address_space(1))) void*)g,
      (__attribute__((address_space(3))) void*)l, 16, 0, 0);
}

#define GBAR()  asm volatile("s_barrier" ::: "memory")
#define WVM0()  asm volatile("s_waitcnt vmcnt(0)" ::: "memory")

// ---------------- prep kernels ----------------

__global__ void k_cvt_bf16(const float* __restrict__ in, u16* __restrict__ out, int n4) {
  int i = blockIdx.x * blockDim.x + threadIdx.x;
  if (i >= n4) return;
  const float4 v = ((const float4*)in)[i];
  ushort4 o;
  o.x = f2bf(v.x); o.y = f2bf(v.y); o.z = f2bf(v.z); o.w = f2bf(v.w);
  ((ushort4*)out)[i] = o;
}

// W [EMB][N3] fp32 -> Wt [N3][EMB] bf16
__global__ void k_transpose_w(const float* __restrict__ W, u16* __restrict__ Wt) {
  __shared__ float t[32][33];
  int n0 = blockIdx.x * 32, k0 = blockIdx.y * 32;
  int tx = threadIdx.x, ty = threadIdx.y;
  #pragma unroll
  for (int i = ty; i < 32; i += 8)
    t[i][tx] = W[(size_t)(k0 + i) * N3 + n0 + tx];
  __syncthreads();
  #pragma unroll
  for (int i = ty; i < 32; i += 8)
    Wt[(size_t)(n0 + i) * EMB + k0 + tx] = f2bf(t[tx][i]);
}

// sincos table for t = s*HD + d; double-precision sincos matches numpy fp32 tables
__global__ void k_sincos(float2* __restrict__ tab) {
  int i = blockIdx.x * blockDim.x + threadIdx.x;   // 0 .. SEQ*HD-1
  double t = (double)i;
  tab[i] = make_float2((float)cos(t), (float)sin(t));
}

// ---------------- QKV GEMM: fat-wave 256x384, 4 waves, 1 barrier/K-tile ----------------
// R8 post-mortem: the 8-wave lockstep (2 barriers/phase, 8/K-tile) runs LDS and
// MFMA pipes SERIALLY (per-K-tile 5050 cyc vs MFMA 2065 + LDS 1900); per-wave
// tile capped at 128x64 by the 256-reg budget (2 waves/SIMD); grid 384 -> 1.5
// rounds (x0.75). Fix all three at once: 4 waves (1/SIMD) -> 512-reg budget ->
// per-wave 128x192 (acc[8][12]=384 regs, ~470 total, no spill), block 256x384,
// grid 16x16 = 256 blocks = 1.0 rounds EXACT. Read ratio 40 b128 / 192 MFMA =
// 0.21 -> per-CU LDS (~2200 cyc) < per-SIMD MFMA (~3725 cyc) -> MFMA-bound.
// With 1 wave/SIMD there is no cross-wave pipelining to orchestrate: ONE
// barrier + ONE vmcnt(0) per K-tile; stage(t+1) issued right after, lands a
// full K-tile (~4000 cyc >> 900 HBM) before its wait -> vmcnt(0) is free (the
// m97 barrier-drain disease needs short prefetch distance; ours is a tile).
// The compiler's fine-grained lgkmcnt scheduling (proven m97) interleaves the
// 40 ds_reads under the 192 MFMAs inside the tile.
// Per K-tile per wave: for kk{0,1}: af[8] (8 rd); for tt{0,1}: bfr[6] (6 rd);
// 48 MFMA. Accumulation per element: t asc, kk asc -> bit-identical to R4/R8.
// Swizzle (T2, 0-conflict R1-R8): slot quad = quad ^ (row&7) on the per-lane
// GLOBAL source (LDS dest linear) and on the ds_read quad; fragment rows all
// have row&7 == lq&7, so qsw[kk] = ((kk*4+lr)^(lq&7))*8.
// N-mapping (RoPE pairs in-wave; bijective over 384 cols = 3 heads):
//   wave wc (0,1), group g (0..5): pg = 6*wc+g; head j = pg>>2; strip s4 = pg&3
//   nf = 2g+half -> tile col = j*128 + s4*16 + half*64 + lq.
//   Pair (nf=2g, 2g+1) = (d, d+64) of head j -> in-wave. q/k/v per group
//   (H = 3*bx + j; 384 !| 2048), wave-uniform within the group loop.
__global__ __launch_bounds__(256, 1) void k_gemm_qkv(
    const u16* __restrict__ xb, const u16* __restrict__ wt,
    const float* __restrict__ bias, const float2* __restrict__ tab,
    u16* __restrict__ qb, u16* __restrict__ kb, u16* __restrict__ vbt)
{
  __shared__ __align__(16) u16 lsA[2][BM * BK];   // 32 KB x2
  __shared__ __align__(16) u16 lsB[2][BN * BK];   // 48 KB x2  (160 KB total)
  const int tid = threadIdx.x;            // 0..255
  const int wave = tid >> 6, lane = tid & 63;
  const int lq = lane & 15, lr = lane >> 4;
  const int wr = wave >> 1, wc = wave & 1;
  const int m0 = blockIdx.y * BM, n0 = blockIdx.x * BN;

  auto stA = [&](int t) {                 // 256x64 tile: 8 loads/thread, 32 KB
    const int kt = t * BK;
    u16* dst = lsA[t & 1];
    #pragma unroll
    for (int ii = 0; ii < 8; ++ii) {
      int s = ii * 256 + tid;             // 16B slot 0..2047
      int row = s >> 3, gq = (s & 7) ^ (row & 7);
      async16(xb + (size_t)(m0 + row) * EMB + kt + gq * 8, dst + s * 8);
    }
  };
  auto stB = [&](int t) {                 // 384x64 tile: 12 loads/thread, 48 KB
    const int kt = t * BK;
    u16* dst = lsB[t & 1];
    #pragma unroll
    for (int ii = 0; ii < 12; ++ii) {
      int s = ii * 256 + tid;             // 16B slot 0..3071
      int row = s >> 3, gq = (s & 7) ^ (row & 7);
      async16(wt + (size_t)(n0 + row) * EMB + kt + gq * 8, dst + s * 8);
    }
  };

  f32x4 acc[8][12];
  #pragma unroll
  for (int i = 0; i < 8; ++i)
    #pragma unroll
    for (int j = 0; j < 12; ++j)
      acc[i][j] = f32x4{0.f, 0.f, 0.f, 0.f};

  // per-lane LDS read offsets (u16 units)
  int rbase[12];
  #pragma unroll
  for (int nf = 0; nf < 12; ++nf) {
    int g = nf >> 1, half = nf & 1;
    int pg = 6 * wc + g;
    int col = (pg >> 2) * 128 + (pg & 3) * 16 + half * 64 + lq;
    rbase[nf] = col * BK;
  }
  const int aRow0 = (wr * 128 + lq) * BK;
  int qsw[2];
  qsw[0] = ((0 + lr) ^ (lq & 7)) * 8;
  qsw[1] = ((4 + lr) ^ (lq & 7)) * 8;

  // prologue: stage tile 0
  stA(0); stB(0);

  for (int t = 0; t < NT_K; ++t) {
    WVM0();                                // own stage(t) loads landed (issued a full tile ago)
    GBAR();                                // all waves' stage(t) landed; buf[1-(t&1)] fully consumed
    if (t + 1 < NT_K) { stA(t + 1); stB(t + 1); }

    const u16* Ap = lsA[t & 1];
    const u16* Bp = lsB[t & 1];

    #pragma unroll
    for (int kk = 0; kk < 2; ++kk) {
      bf16x8 af[8];
      #pragma unroll
      for (int mf = 0; mf < 8; ++mf)
        af[mf] = *(const bf16x8*)(Ap + aRow0 + (mf * 16) * BK + qsw[kk]);
      #pragma unroll
      for (int tt = 0; tt < 2; ++tt) {
        bf16x8 bfr[6];
        #pragma unroll
        for (int z = 0; z < 6; ++z)
          bfr[z] = *(const bf16x8*)(Bp + rbase[tt * 6 + z] + qsw[kk]);
        #pragma unroll
        for (int mf = 0; mf < 8; ++mf)
          #pragma unroll
          for (int z = 0; z < 6; ++z)
            acc[mf][tt * 6 + z] = __builtin_amdgcn_mfma_f32_16x16x32_bf16(
                af[mf], bfr[z], acc[mf][tt * 6 + z], 0, 0, 0);
      }
    }
  }

  // ---------------- epilogue (fused bias + RoPE / V-transpose, per pair-group) ----------------
  const int m0w = m0 + wr * 128;
  const int bxH = n0 >> 7;                 // = 3 * blockIdx.x
  #pragma unroll
  for (int g = 0; g < 6; ++g) {
    const int pg = 6 * wc + g;
    const int j = pg >> 2;                 // head within tile (0..2)
    const int s4 = pg & 3;                 // 16-col strip within half-head
    const int H = bxH + j;                 // absolute head index (0..47)
    const int w = H >> 4;                  // 0=q, 1=k, 2=v
    const int h = H & 15;
    const int d1 = s4 * 16 + lq;           // d within head, in [0,64); partner d1+64
    const float b1 = bias[n0 + j * 128 + d1];
    const float b2 = bias[n0 + j * 128 + d1 + 64];

    if (w == 2) {
      // V: transpose to [B,H,D,SEQP], 4 consecutive s per 8B store
      #pragma unroll
      for (int mf = 0; mf < 8; ++mf) {
        int mg0 = m0w + mf * 16 + lr * 4;
        int b = mg0 >> 11, s0 = mg0 & 2047;
        ushort4 pk;
        pk.x = f2bf(acc[mf][2 * g][0] + b1);
        pk.y = f2bf(acc[mf][2 * g][1] + b1);
        pk.z = f2bf(acc[mf][2 * g][2] + b1);
        pk.w = f2bf(acc[mf][2 * g][3] + b1);
        *(ushort4*)(vbt + ((size_t)(b * NH + h) * HD + d1) * SEQP + s0) = pk;
        pk.x = f2bf(acc[mf][2 * g + 1][0] + b2);
        pk.y = f2bf(acc[mf][2 * g + 1][1] + b2);
        pk.z = f2bf(acc[mf][2 * g + 1][2] + b2);
        pk.w = f2bf(acc[mf][2 * g + 1][3] + b2);
        *(ushort4*)(vbt + ((size_t)(b * NH + h) * HD + d1 + 64) * SEQP + s0) = pk;
      }
    } else {
      u16* basep = (w == 0) ? qb : kb;
      const float qs = (w == 0) ? 0.12751569843736827f : 1.0f;  // log2(e)/sqrt(128) into q
      #pragma unroll
      for (int mf = 0; mf < 8; ++mf)
        #pragma unroll
        for (int r = 0; r < 4; ++r) {
          int mg = m0w + mf * 16 + lr * 4 + r;
          int b = mg >> 11, s = mg & 2047;
          u16* dst = basep + ((size_t)(b * NH + h) * SEQ + s) * HD;
          float c1 = acc[mf][2 * g][r]     + b1;
          float c2 = acc[mf][2 * g + 1][r] + b2;
          float2 s1 = tab[s * HD + d1];
          float2 s2 = tab[s * HD + d1 + 64];
          dst[d1]      = f2bf((c1 * s1.x - c2 * s1.y) * qs);
          dst[d1 + 64] = f2bf((c2 * s2.x + c1 * s2.y) * qs);
        }
    }
  }
}

// ---------------- flash attention (unchanged; round-4 structure + XCD-aware remap) ----------------
__global__ __launch_bounds__(128, 2) void k_flash(
    const u16* __restrict__ qb, const u16* __restrict__ kb,
    const u16* __restrict__ vbt, float* __restrict__ out)
{
  __shared__ __align__(16) u16 lsK[2][KT * HD];   // [key][d] 16B-grp ^= key&7    (8 KB x2)
  __shared__ __align__(16) u16 lsV[2][HD * KT];   // [d][key] 16B-grp ^= (d>>1)&3 (8 KB x2)
  __shared__ __align__(16) u16 lsP[2][WQ * KT];   // per-wave [qrow][key], 8B-grp ^= row&6

  const int tid = threadIdx.x;            // 0..127
  const int wave = tid >> 6, lane = tid & 63;
  const int lq = lane & 15, lr = lane >> 4;
  const int i = blockIdx.x;               // 0..1023
  const int xcd = i & 7, j = i >> 3;      // j: 0..127
  const int bh = xcd * 4 + (j >> 5);      // 4 heads per XCD
  const int q0 = (j & 31) * QT;
  const u16* Qg = qb + ((size_t)bh * SEQ + q0 + wave * WQ) * HD;
  const u16* Kg = kb + (size_t)bh * SEQ * HD;
  const u16* Vg = vbt + (size_t)bh * HD * SEQP;

  auto stage = [&](int tile, int buf) {
    const int k0 = tile * KT;
    #pragma unroll
    for (int ii = 0; ii < 4; ++ii) {
      int c = tid + ii * 128;
      int key = c >> 4, grp = c & 15;
      async16(Kg + (size_t)(k0 + key) * HD + ((grp ^ (key & 7)) * 8), lsK[buf] + c * 8);
    }
    #pragma unroll
    for (int ii = 0; ii < 4; ++ii) {
      int c = tid + ii * 128;
      int d = c >> 2, g2 = c & 3;
      async16(Vg + (size_t)d * SEQP + k0 + ((g2 ^ ((d >> 1) & 3)) * 8), lsV[buf] + c * 8);
    }
  };

  stage(0, 0);

  bf16x8 qf[2][4];
  #pragma unroll
  for (int qq = 0; qq < 2; ++qq)
    #pragma unroll
    for (int ks = 0; ks < 4; ++ks)
      qf[qq][ks] = *(const bf16x8*)(Qg + (size_t)(qq * 16 + lq) * HD + ks * 32 + lr * 8);

  f32x4 acc_o[2][8];
  float lsum[2] = {0.f, 0.f};
  #pragma unroll
  for (int mb = 0; mb < 2; ++mb)
    #pragma unroll
    for (int nb = 0; nb < 8; ++nb) acc_o[mb][nb] = f32x4{0.f, 0.f, 0.f, 0.f};

  for (int t = 0; t < NTILE; ++t) {
    const int p = t & 1;
    __syncthreads();                 // drains stage(t); all waves done with buf 1-p
    if (t + 1 < NTILE) stage(t + 1, 1 - p);

    // S^T = K Q^T : 32 keys x 32 q-rows per wave
    f32x4 sacc[2][2];
    #pragma unroll
    for (int kbi = 0; kbi < 2; ++kbi)
      #pragma unroll
      for (int qq = 0; qq < 2; ++qq) sacc[kbi][qq] = f32x4{0.f, 0.f, 0.f, 0.f};
    #pragma unroll
    for (int ks = 0; ks < 4; ++ks) {
      bf16x8 kf[2];
      #pragma unroll
      for (int kbi = 0; kbi < 2; ++kbi) {
        int key = kbi * 16 + lq;
        int g = (ks * 4 + lr) ^ (key & 7);
        kf[kbi] = *(const bf16x8*)(lsK[p] + key * HD + g * 8);
      }
      #pragma unroll
      for (int kbi = 0; kbi < 2; ++kbi)
        #pragma unroll
        for (int qq = 0; qq < 2; ++qq)
          sacc[kbi][qq] = __builtin_amdgcn_mfma_f32_16x16x32_bf16(kf[kbi], qf[qq][ks], sacc[kbi][qq], 0, 0, 0);
    }

    // P = exp2(S) (log2e folded into q); packed b64 writes (4 consecutive keys/lane)
    #pragma unroll
    for (int kbi = 0; kbi < 2; ++kbi)
      #pragma unroll
      for (int qq = 0; qq < 2; ++qq) {
        float p0 = __builtin_amdgcn_exp2f(sacc[kbi][qq][0]);
        float p1 = __builtin_amdgcn_exp2f(sacc[kbi][qq][1]);
        float p2 = __builtin_amdgcn_exp2f(sacc[kbi][qq][2]);
        float p3 = __builtin_amdgcn_exp2f(sacc[kbi][qq][3]);
        lsum[qq] += (p0 + p1) + (p2 + p3);
        int row = qq * 16 + lq;
        int g = kbi * 4 + lr;
        int gp = g ^ (row & 6);
        uint2 pk;
        pk.x = (uint32_t)f2bf(p0) | ((uint32_t)f2bf(p1) << 16);
        pk.y = (uint32_t)f2bf(p2) | ((uint32_t)f2bf(p3) << 16);
        *(uint2*)(lsP[wave] + row * KT + gp * 4) = pk;
      }

    // O += P V
    bf16x8 ap[2];
    #pragma unroll
    for (int mb = 0; mb < 2; ++mb) {
      int row = mb * 16 + lq;
      int gp = (2 * lr) ^ (row & 6);
      ap[mb] = *(const bf16x8*)(lsP[wave] + row * KT + gp * 4);
    }
    #pragma unroll
    for (int nb = 0; nb < 8; ++nb) {
      int d = nb * 16 + lq;
      int g2 = lr ^ ((d >> 1) & 3);
      bf16x8 bv = *(const bf16x8*)(lsV[p] + d * KT + g2 * 8);
      #pragma unroll
      for (int mb = 0; mb < 2; ++mb)
        acc_o[mb][nb] = __builtin_amdgcn_mfma_f32_16x16x32_bf16(ap[mb], bv[0] == bv[0] ? bv : bv, acc_o[mb][nb], 0, 0, 0);
    }
  }

  float inv[2];
  #pragma unroll
  for (int qq = 0; qq < 2; ++qq) {
    float s = lsum[qq];
    s += __shfl_xor(s, 16);
    s += __shfl_xor(s, 32);
    inv[qq] = 1.0f / s;
  }
  const int b = bh >> 4, h = bh & 15;
  #pragma unroll
  for (int mb = 0; mb < 2; ++mb)
    #pragma unroll
    for (int r = 0; r < 4; ++r) {
      float iv = __shfl(inv[mb], lr * 4 + r);
      int row = wave * WQ + mb * 16 + lr * 4 + r;
      int sq = q0 + row;
      float* op = out + (((size_t)b * SEQ + sq) * NH + h) * HD;
      #pragma unroll
      for (int nb = 0; nb < 8; ++nb)
        op[nb * 16 + lq] = acc_o[mb][nb][r] * iv;
    }
}

// ---------------- launch ----------------

extern "C" void kernel_launch(void* const* d_in, const int* in_sizes, int n_in,
                              void* d_out, int out_size, void* d_ws, size_t ws_size,
                              hipStream_t stream) {
  (void)in_sizes; (void)n_in; (void)out_size; (void)ws_size;
  const float* x    = (const float*)d_in[0];
  const float* W    = (const float*)d_in[1];
  const float* bias = (const float*)d_in[2];
  float* out = (float*)d_out;

  char* p = (char*)d_ws;
  u16* xb  = (u16*)p;  p += (size_t)MM * EMB * 2;                     // 16.8 MB
  u16* wt  = (u16*)p;  p += (size_t)N3 * EMB * 2;                     // 25.2 MB
  u16* qb  = (u16*)p;  p += (size_t)NUM_B * NH * SEQ * HD * 2;        // 16.8 MB
  u16* kb  = (u16*)p;  p += (size_t)NUM_B * NH * SEQ * HD * 2;        // 16.8 MB
  u16* vbt = (u16*)p;  p += (size_t)NUM_B * NH * HD * SEQP * 2;       // 17.0 MB
  float2* tab = (float2*)p;                                           // 2.1 MB

  k_cvt_bf16<<<(MM * EMB / 4 + 255) / 256, 256, 0, stream>>>(x, xb, MM * EMB / 4);
  k_transpose_w<<<dim3(N3 / 32, EMB / 32), dim3(32, 8), 0, stream>>>(W, wt);
  k_sincos<<<(SEQ * HD) / 256, 256, 0, stream>>>(tab);
  k_gemm_qkv<<<dim3(N3 / BN, MM / BM), 256, 0, stream>>>(xb, wt, bias, tab, qb, kb, vbt);
  k_flash<<<SEQ / QT * NUM_B * NH, 128, 0, stream>>>(qb, kb, vbt, out);
}

// Round 10
// 267.739 us; speedup vs baseline: 3.0221x; 3.0221x over previous
//
#include <hip/hip_runtime.h>
#include <stdint.h>

typedef unsigned short u16;
typedef __attribute__((ext_vector_type(8))) short bf16x8;   // 8 bf16 = 4 VGPRs
typedef __attribute__((ext_vector_type(4))) float f32x4;

#define NUM_B 2
#define SEQ   2048
#define SEQP  2080      // padded V row stride
#define NH    16
#define HD    128
#define EMB   2048      // NH*HD
#define N3    6144      // 3*EMB
#define MM    4096      // NUM_B*SEQ
#define QT    64        // flash q-rows per block (2 waves)
#define WQ    32        // flash q-rows per wave
#define KT    32        // flash keys per k-tile
#define NTILE (SEQ / KT)

// ---- GEMM tile: 256x384, BK=64, 12 waves of the PROVEN 128x64 shape ----
#define BM 256
#define BN 384
#define BK 64
#define NT_K (EMB / BK)   // 32 K-tiles

__device__ __forceinline__ u16 f2bf(float f) {
  union { float f; unsigned u; } c; c.f = f;
  return (u16)((c.u + 0x7FFFu + ((c.u >> 16) & 1u)) >> 16);   // RNE
}
__device__ __forceinline__ void async16(const void* g, void* l) {
  __builtin_amdgcn_global_load_lds(
      (const __attribute__((address_space(1))) void*)g,
      (__attribute__((address_space(3))) void*)l, 16, 0, 0);
}

#define GBAR()  asm volatile("s_barrier" ::: "memory")
#define WVM0()  asm volatile("s_waitcnt vmcnt(0)" ::: "memory")

// ---------------- prep kernels ----------------

__global__ void k_cvt_bf16(const float* __restrict__ in, u16* __restrict__ out, int n4) {
  int i = blockIdx.x * blockDim.x + threadIdx.x;
  if (i >= n4) return;
  const float4 v = ((const float4*)in)[i];
  ushort4 o;
  o.x = f2bf(v.x); o.y = f2bf(v.y); o.z = f2bf(v.z); o.w = f2bf(v.w);
  ((ushort4*)out)[i] = o;
}

// W [EMB][N3] fp32 -> Wt [N3][EMB] bf16
__global__ void k_transpose_w(const float* __restrict__ W, u16* __restrict__ Wt) {
  __shared__ float t[32][33];
  int n0 = blockIdx.x * 32, k0 = blockIdx.y * 32;
  int tx = threadIdx.x, ty = threadIdx.y;
  #pragma unroll
  for (int i = ty; i < 32; i += 8)
    t[i][tx] = W[(size_t)(k0 + i) * N3 + n0 + tx];
  __syncthreads();
  #pragma unroll
  for (int i = ty; i < 32; i += 8)
    Wt[(size_t)(n0 + i) * EMB + k0 + tx] = f2bf(t[tx][i]);
}

// sincos table for t = s*HD + d; double-precision sincos matches numpy fp32 tables
__global__ void k_sincos(float2* __restrict__ tab) {
  int i = blockIdx.x * blockDim.x + threadIdx.x;   // 0 .. SEQ*HD-1
  double t = (double)i;
  tab[i] = make_float2((float)cos(t), (float)sin(t));
}

// ---------------- QKV GEMM: 256x384, 12 waves (2M x 6N), simple 1-barrier loop ----------------
// R9 post-mortem: compiler caps arch VGPRs at 256 -> acc[8][12] spilled to
// scratch (WRITE 1.3 GB). Hard constraint (R6+R9): per-wave acc[8][4]=128 max.
// This round keeps the PROVEN per-wave 128x64 / acc[8][4] shape (R4: 124-128
// VGPR, no spill) and fixes the two measured losses:
//  (a) grid tail: 12 waves/block -> block 256x384 -> grid 16x16 = 256 blocks
//      = exactly 1.0 rounds at 1 block/CU (LDS 160 KB, launch-proven R6/R9).
//  (b) lockstep serialization (R4/R8: 8 barriers/K-tile force chip-wide
//      LDS-burst/MFMA-burst alternation): ONE vmcnt(0) + ONE barrier per
//      K-tile (R9 schedule, structurally sound); prefetch distance = full
//      K-tile compute (~3000 cyc >> 900-cyc HBM) so the drain is free; the
//      compiler's fine-grained lgkmcnt scheduling (m97-proven) + 3-wave/SIMD
//      skew overlaps the 24 ds_reads with the 48 MFMAs per wave per tile.
// Hazards: stage(t+1)->buf[(t+1)&1] is issued AFTER iter-t's barrier; every
// wave's reads of that buffer happened in iter t-1, before that barrier. Own
// stage(t) awaited by WVM0 at iter t; other waves' by their WVM0 + barrier.
// Per-CU per K-tile: LDS 288 b128 (~3456 cyc) vs MFMA ~3090 cyc -> LDS-
// co-critical; ceiling ~89% MfmaUtil.
// VGPR: __launch_bounds__(768,3) -> cap ~170 (3 waves/SIMD). Live set kept
// small: bfr[4] (16) + af pair (8) + acc (128) + addr ~= 165.
// Swizzle (T2, 0-conflict R1-R9): slot quad = quad ^ (row&7) on per-lane
// GLOBAL source (LDS dest linear) + on ds_read quad; qsw[kk]=((kk*4+lr)^(lq&7))*8.
// N-mapping (RoPE pairs in-wave; bijective over 384 = 3 heads x 128):
//   wave wc (0..5), group g (0,1): pg = 2*wc+g (0..11); head j = pg>>2;
//   strip s4 = pg&3; nf = 2g+half -> tile col = j*128 + s4*16 + half*64 + lq.
//   Pair (nf=2g, 2g+1) = (d, d+64) of head j, in-wave. q/k/v per pg
//   (H = 3*blockIdx.x + j), wave-uniform in the g loop.
// Accumulation per element: t asc, kk asc -> bit-identical to R4/R8.
__global__ __launch_bounds__(768, 3) void k_gemm_qkv(
    const u16* __restrict__ xb, const u16* __restrict__ wt,
    const float* __restrict__ bias, const float2* __restrict__ tab,
    u16* __restrict__ qb, u16* __restrict__ kb, u16* __restrict__ vbt)
{
  __shared__ __align__(16) u16 lsA[2][BM * BK];   // 32 KB x2
  __shared__ __align__(16) u16 lsB[2][BN * BK];   // 48 KB x2  (160 KB total)
  const int tid = threadIdx.x;            // 0..767
  const int wave = tid >> 6, lane = tid & 63;
  const int lq = lane & 15, lr = lane >> 4;
  const int wr = wave / 6, wc = wave % 6;
  const int m0 = blockIdx.y * BM, n0 = blockIdx.x * BN;

  auto stA = [&](int t) {                 // 256x64: 2048 slots; waves 8-11 do 2, rest 3
    const int kt = t * BK;
    u16* dst = lsA[t & 1];
    #pragma unroll
    for (int ii = 0; ii < 3; ++ii) {
      int s = ii * 768 + tid;
      if (s < 2048) {                     // ii==2 -> tid<512: wave-uniform guard
        int row = s >> 3, gq = (s & 7) ^ (row & 7);
        async16(xb + (size_t)(m0 + row) * EMB + kt + gq * 8, dst + s * 8);
      }
    }
  };
  auto stB = [&](int t) {                 // 384x64: 3072 slots = 4/thread exact
    const int kt = t * BK;
    u16* dst = lsB[t & 1];
    #pragma unroll
    for (int ii = 0; ii < 4; ++ii) {
      int s = ii * 768 + tid;
      int row = s >> 3, gq = (s & 7) ^ (row & 7);
      async16(wt + (size_t)(n0 + row) * EMB + kt + gq * 8, dst + s * 8);
    }
  };

  f32x4 acc[8][4];
  #pragma unroll
  for (int i = 0; i < 8; ++i)
    #pragma unroll
    for (int j = 0; j < 4; ++j)
      acc[i][j] = f32x4{0.f, 0.f, 0.f, 0.f};

  // per-lane LDS read offsets (u16 units)
  int rbase[4];
  #pragma unroll
  for (int nf = 0; nf < 4; ++nf) {
    int pg = 2 * wc + (nf >> 1);
    int col = (pg >> 2) * 128 + (pg & 3) * 16 + (nf & 1) * 64 + lq;
    rbase[nf] = col * BK;
  }
  const int aRow0 = (wr * 128 + lq) * BK;
  int qsw[2];
  qsw[0] = ((0 + lr) ^ (lq & 7)) * 8;
  qsw[1] = ((4 + lr) ^ (lq & 7)) * 8;

  // prologue: stage tile 0
  stA(0); stB(0);

  for (int t = 0; t < NT_K; ++t) {
    WVM0();                                // own stage(t) landed
    GBAR();                                // everyone's stage(t) landed; buf[(t+1)&1] fully consumed
    if (t + 1 < NT_K) { stA(t + 1); stB(t + 1); }

    const u16* Ap = lsA[t & 1];
    const u16* Bp = lsB[t & 1];

    #pragma unroll
    for (int kk = 0; kk < 2; ++kk) {
      bf16x8 bfr[4];
      #pragma unroll
      for (int nf = 0; nf < 4; ++nf)
        bfr[nf] = *(const bf16x8*)(Bp + rbase[nf] + qsw[kk]);
      #pragma unroll
      for (int mp = 0; mp < 4; ++mp) {     // af in pairs: keeps live regs <= cap
        bf16x8 af0 = *(const bf16x8*)(Ap + aRow0 + ((2 * mp) * 16) * BK + qsw[kk]);
        bf16x8 af1 = *(const bf16x8*)(Ap + aRow0 + ((2 * mp + 1) * 16) * BK + qsw[kk]);
        #pragma unroll
        for (int nf = 0; nf < 4; ++nf) {
          acc[2 * mp][nf]     = __builtin_amdgcn_mfma_f32_16x16x32_bf16(af0, bfr[nf], acc[2 * mp][nf], 0, 0, 0);
          acc[2 * mp + 1][nf] = __builtin_amdgcn_mfma_f32_16x16x32_bf16(af1, bfr[nf], acc[2 * mp + 1][nf], 0, 0, 0);
        }
      }
    }
  }

  // ---------------- epilogue (fused bias + RoPE / V-transpose, per pair-group) ----------------
  const int m0w = m0 + wr * 128;
  const int bxH = n0 >> 7;                 // = 3 * blockIdx.x
  #pragma unroll
  for (int g = 0; g < 2; ++g) {
    const int pg = 2 * wc + g;
    const int j = pg >> 2;                 // head within tile (0..2)
    const int s4 = pg & 3;                 // 16-col strip within half-head
    const int H = bxH + j;                 // absolute head index (0..47)
    const int w = H >> 4;                  // 0=q, 1=k, 2=v
    const int h = H & 15;
    const int d1 = s4 * 16 + lq;           // d within head, in [0,64); partner d1+64
    const float b1 = bias[n0 + j * 128 + d1];
    const float b2 = bias[n0 + j * 128 + d1 + 64];

    if (w == 2) {
      // V: transpose to [B,H,D,SEQP], 4 consecutive s per 8B store
      #pragma unroll
      for (int mf = 0; mf < 8; ++mf) {
        int mg0 = m0w + mf * 16 + lr * 4;
        int b = mg0 >> 11, s0 = mg0 & 2047;
        ushort4 pk;
        pk.x = f2bf(acc[mf][2 * g][0] + b1);
        pk.y = f2bf(acc[mf][2 * g][1] + b1);
        pk.z = f2bf(acc[mf][2 * g][2] + b1);
        pk.w = f2bf(acc[mf][2 * g][3] + b1);
        *(ushort4*)(vbt + ((size_t)(b * NH + h) * HD + d1) * SEQP + s0) = pk;
        pk.x = f2bf(acc[mf][2 * g + 1][0] + b2);
        pk.y = f2bf(acc[mf][2 * g + 1][1] + b2);
        pk.z = f2bf(acc[mf][2 * g + 1][2] + b2);
        pk.w = f2bf(acc[mf][2 * g + 1][3] + b2);
        *(ushort4*)(vbt + ((size_t)(b * NH + h) * HD + d1 + 64) * SEQP + s0) = pk;
      }
    } else {
      u16* basep = (w == 0) ? qb : kb;
      const float qs = (w == 0) ? 0.12751569843736827f : 1.0f;  // log2(e)/sqrt(128) into q
      #pragma unroll
      for (int mf = 0; mf < 8; ++mf)
        #pragma unroll
        for (int r = 0; r < 4; ++r) {
          int mg = m0w + mf * 16 + lr * 4 + r;
          int b = mg >> 11, s = mg & 2047;
          u16* dst = basep + ((size_t)(b * NH + h) * SEQ + s) * HD;
          float c1 = acc[mf][2 * g][r]     + b1;
          float c2 = acc[mf][2 * g + 1][r] + b2;
          float2 s1 = tab[s * HD + d1];
          float2 s2 = tab[s * HD + d1 + 64];
          dst[d1]      = f2bf((c1 * s1.x - c2 * s1.y) * qs);
          dst[d1 + 64] = f2bf((c2 * s2.x + c1 * s2.y) * qs);
        }
    }
  }
}

// ---------------- flash attention (unchanged; round-4 structure + XCD-aware remap) ----------------
__global__ __launch_bounds__(128, 2) void k_flash(
    const u16* __restrict__ qb, const u16* __restrict__ kb,
    const u16* __restrict__ vbt, float* __restrict__ out)
{
  __shared__ __align__(16) u16 lsK[2][KT * HD];   // [key][d] 16B-grp ^= key&7    (8 KB x2)
  __shared__ __align__(16) u16 lsV[2][HD * KT];   // [d][key] 16B-grp ^= (d>>1)&3 (8 KB x2)
  __shared__ __align__(16) u16 lsP[2][WQ * KT];   // per-wave [qrow][key], 8B-grp ^= row&6

  const int tid = threadIdx.x;            // 0..127
  const int wave = tid >> 6, lane = tid & 63;
  const int lq = lane & 15, lr = lane >> 4;
  const int i = blockIdx.x;               // 0..1023
  const int xcd = i & 7, j = i >> 3;      // j: 0..127
  const int bh = xcd * 4 + (j >> 5);      // 4 heads per XCD
  const int q0 = (j & 31) * QT;
  const u16* Qg = qb + ((size_t)bh * SEQ + q0 + wave * WQ) * HD;
  const u16* Kg = kb + (size_t)bh * SEQ * HD;
  const u16* Vg = vbt + (size_t)bh * HD * SEQP;

  auto stage = [&](int tile, int buf) {
    const int k0 = tile * KT;
    #pragma unroll
    for (int ii = 0; ii < 4; ++ii) {
      int c = tid + ii * 128;
      int key = c >> 4, grp = c & 15;
      async16(Kg + (size_t)(k0 + key) * HD + ((grp ^ (key & 7)) * 8), lsK[buf] + c * 8);
    }
    #pragma unroll
    for (int ii = 0; ii < 4; ++ii) {
      int c = tid + ii * 128;
      int d = c >> 2, g2 = c & 3;
      async16(Vg + (size_t)d * SEQP + k0 + ((g2 ^ ((d >> 1) & 3)) * 8), lsV[buf] + c * 8);
    }
  };

  stage(0, 0);

  bf16x8 qf[2][4];
  #pragma unroll
  for (int qq = 0; qq < 2; ++qq)
    #pragma unroll
    for (int ks = 0; ks < 4; ++ks)
      qf[qq][ks] = *(const bf16x8*)(Qg + (size_t)(qq * 16 + lq) * HD + ks * 32 + lr * 8);

  f32x4 acc_o[2][8];
  float lsum[2] = {0.f, 0.f};
  #pragma unroll
  for (int mb = 0; mb < 2; ++mb)
    #pragma unroll
    for (int nb = 0; nb < 8; ++nb) acc_o[mb][nb] = f32x4{0.f, 0.f, 0.f, 0.f};

  for (int t = 0; t < NTILE; ++t) {
    const int p = t & 1;
    __syncthreads();                 // drains stage(t); all waves done with buf 1-p
    if (t + 1 < NTILE) stage(t + 1, 1 - p);

    // S^T = K Q^T : 32 keys x 32 q-rows per wave
    f32x4 sacc[2][2];
    #pragma unroll
    for (int kbi = 0; kbi < 2; ++kbi)
      #pragma unroll
      for (int qq = 0; qq < 2; ++qq) sacc[kbi][qq] = f32x4{0.f, 0.f, 0.f, 0.f};
    #pragma unroll
    for (int ks = 0; ks < 4; ++ks) {
      bf16x8 kf[2];
      #pragma unroll
      for (int kbi = 0; kbi < 2; ++kbi) {
        int key = kbi * 16 + lq;
        int g = (ks * 4 + lr) ^ (key & 7);
        kf[kbi] = *(const bf16x8*)(lsK[p] + key * HD + g * 8);
      }
      #pragma unroll
      for (int kbi = 0; kbi < 2; ++kbi)
        #pragma unroll
        for (int qq = 0; qq < 2; ++qq)
          sacc[kbi][qq] = __builtin_amdgcn_mfma_f32_16x16x32_bf16(kf[kbi], qf[qq][ks], sacc[kbi][qq], 0, 0, 0);
    }

    // P = exp2(S) (log2e folded into q); packed b64 writes (4 consecutive keys/lane)
    #pragma unroll
    for (int kbi = 0; kbi < 2; ++kbi)
      #pragma unroll
      for (int qq = 0; qq < 2; ++qq) {
        float p0 = __builtin_amdgcn_exp2f(sacc[kbi][qq][0]);
        float p1 = __builtin_amdgcn_exp2f(sacc[kbi][qq][1]);
        float p2 = __builtin_amdgcn_exp2f(sacc[kbi][qq][2]);
        float p3 = __builtin_amdgcn_exp2f(sacc[kbi][qq][3]);
        lsum[qq] += (p0 + p1) + (p2 + p3);
        int row = qq * 16 + lq;
        int g = kbi * 4 + lr;
        int gp = g ^ (row & 6);
        uint2 pk;
        pk.x = (uint32_t)f2bf(p0) | ((uint32_t)f2bf(p1) << 16);
        pk.y = (uint32_t)f2bf(p2) | ((uint32_t)f2bf(p3) << 16);
        *(uint2*)(lsP[wave] + row * KT + gp * 4) = pk;
      }

    // O += P V
    bf16x8 ap[2];
    #pragma unroll
    for (int mb = 0; mb < 2; ++mb) {
      int row = mb * 16 + lq;
      int gp = (2 * lr) ^ (row & 6);
      ap[mb] = *(const bf16x8*)(lsP[wave] + row * KT + gp * 4);
    }
    #pragma unroll
    for (int nb = 0; nb < 8; ++nb) {
      int d = nb * 16 + lq;
      int g2 = lr ^ ((d >> 1) & 3);
      bf16x8 bv = *(const bf16x8*)(lsV[p] + d * KT + g2 * 8);
      #pragma unroll
      for (int mb = 0; mb < 2; ++mb)
        acc_o[mb][nb] = __builtin_amdgcn_mfma_f32_16x16x32_bf16(ap[mb], bv[0] == bv[0] ? bv : bv, acc_o[mb][nb], 0, 0, 0);
    }
  }

  float inv[2];
  #pragma unroll
  for (int qq = 0; qq < 2; ++qq) {
    float s = lsum[qq];
    s += __shfl_xor(s, 16);
    s += __shfl_xor(s, 32);
    inv[qq] = 1.0f / s;
  }
  const int b = bh >> 4, h = bh & 15;
  #pragma unroll
  for (int mb = 0; mb < 2; ++mb)
    #pragma unroll
    for (int r = 0; r < 4; ++r) {
      float iv = __shfl(inv[mb], lr * 4 + r);
      int row = wave * WQ + mb * 16 + lr * 4 + r;
      int sq = q0 + row;
      float* op = out + (((size_t)b * SEQ + sq) * NH + h) * HD;
      #pragma unroll
      for (int nb = 0; nb < 8; ++nb)
        op[nb * 16 + lq] = acc_o[mb][nb][r] * iv;
    }
}

// ---------------- launch ----------------

extern "C" void kernel_launch(void* const* d_in, const int* in_sizes, int n_in,
                              void* d_out, int out_size, void* d_ws, size_t ws_size,
                              hipStream_t stream) {
  (void)in_sizes; (void)n_in; (void)out_size; (void)ws_size;
  const float* x    = (const float*)d_in[0];
  const float* W    = (const float*)d_in[1];
  const float* bias = (const float*)d_in[2];
  float* out = (float*)d_out;

  char* p = (char*)d_ws;
  u16* xb  = (u16*)p;  p += (size_t)MM * EMB * 2;                     // 16.8 MB
  u16* wt  = (u16*)p;  p += (size_t)N3 * EMB * 2;                     // 25.2 MB
  u16* qb  = (u16*)p;  p += (size_t)NUM_B * NH * SEQ * HD * 2;        // 16.8 MB
  u16* kb  = (u16*)p;  p += (size_t)NUM_B * NH * SEQ * HD * 2;        // 16.8 MB
  u16* vbt = (u16*)p;  p += (size_t)NUM_B * NH * HD * SEQP * 2;       // 17.0 MB
  float2* tab = (float2*)p;                                           // 2.1 MB

  k_cvt_bf16<<<(MM * EMB / 4 + 255) / 256, 256, 0, stream>>>(x, xb, MM * EMB / 4);
  k_transpose_w<<<dim3(N3 / 32, EMB / 32), dim3(32, 8), 0, stream>>>(W, wt);
  k_sincos<<<(SEQ * HD) / 256, 256, 0, stream>>>(tab);
  k_gemm_qkv<<<dim3(N3 / BN, MM / BM), 768, 0, stream>>>(xb, wt, bias, tab, qb, kb, vbt);
  k_flash<<<SEQ / QT * NUM_B * NH, 128, 0, stream>>>(qb, kb, vbt, out);
}

// Round 11
// 242.810 us; speedup vs baseline: 3.3324x; 1.1027x over previous
//
#include <hip/hip_runtime.h>
#include <stdint.h>

typedef unsigned short u16;
typedef __attribute__((ext_vector_type(8))) short bf16x8;   // 8 bf16 = 4 VGPRs
typedef __attribute__((ext_vector_type(4))) float f32x4;

#define NUM_B 2
#define SEQ   2048
#define SEQP  2080      // padded V row stride
#define NH    16
#define HD    128
#define EMB   2048      // NH*HD
#define N3    6144      // 3*EMB
#define MM    4096      // NUM_B*SEQ
#define QT    64        // flash q-rows per block (2 waves)
#define WQ    32        // flash q-rows per wave
#define KT    32        // flash keys per k-tile
#define NTILE (SEQ / KT)

// ---- GEMM tile params: m201-geometry 256x256, BK=64, 8 waves (R4 optimum) ----
#define BM 256
#define BN 256
#define BK 64
#define NT_K (EMB / BK)   // 32 K-tiles, 16 iterations of 2

__device__ __forceinline__ u16 f2bf(float f) {
  union { float f; unsigned u; } c; c.f = f;
  return (u16)((c.u + 0x7FFFu + ((c.u >> 16) & 1u)) >> 16);   // RNE
}
__device__ __forceinline__ void async16(const void* g, void* l) {
  __builtin_amdgcn_global_load_lds(
      (const __attribute__((address_space(1))) void*)g,
      (__attribute__((address_space(3))) void*)l, 16, 0, 0);
}

#define GBAR()   asm volatile("s_barrier" ::: "memory")
#define WLGKM0() asm volatile("s_waitcnt lgkmcnt(0)" ::: "memory")

// ---------------- prep kernels ----------------

// bf16 cast for x, with the RoPE sincos table fused into the first 262144
// threads (saves one launch; double-precision sincos matches numpy fp32 tables)
__global__ void k_cvt_bf16(const float* __restrict__ in, u16* __restrict__ out,
                           float2* __restrict__ tab, int n4) {
  int i = blockIdx.x * blockDim.x + threadIdx.x;
  if (i >= n4) return;
  const float4 v = ((const float4*)in)[i];
  ushort4 o;
  o.x = f2bf(v.x); o.y = f2bf(v.y); o.z = f2bf(v.z); o.w = f2bf(v.w);
  ((ushort4*)out)[i] = o;
  if (i < SEQ * HD) {
    double t = (double)i;
    tab[i] = make_float2((float)cos(t), (float)sin(t));
  }
}

// W [EMB][N3] fp32 -> Wt [N3][EMB] bf16
__global__ void k_transpose_w(const float* __restrict__ W, u16* __restrict__ Wt) {
  __shared__ float t[32][33];
  int n0 = blockIdx.x * 32, k0 = blockIdx.y * 32;
  int tx = threadIdx.x, ty = threadIdx.y;
  #pragma unroll
  for (int i = ty; i < 32; i += 8)
    t[i][tx] = W[(size_t)(k0 + i) * N3 + n0 + tx];
  __syncthreads();
  #pragma unroll
  for (int i = ty; i < 32; i += 8)
    Wt[(size_t)(n0 + i) * EMB + k0 + tx] = f2bf(t[tx][i]);
}

// ---------------- QKV GEMM: 256x256 8-phase template (R4, measured 134.8 us) ----------------
// Geometry: 8 waves = 2(M-half wr) x 4(N-quarter wc); per-wave C = 8mf x 4nf
// 16x16 frags; acc[8][4] (in AGPRs; 128 VGPR + 128 AGPR = exact 256 budget at
// __launch_bounds__(512,2) -> zero spill, verified WRITE_SIZE ~50 MB).
// LDS: lsA[2][256*64], lsB[2][256*64] = 128 KB; even K-tiles -> buf0, odd ->
// buf1. Iteration = 2 K-tiles (t0,t1), 8 phases; each phase stages ONE
// half-tile (2 async16/thread):
//   P1: A(t1)h0   P2: A(t1)h1   P3: B(t0+2)h0  P4: B(t0+2)h1 + vmcnt(4)
//   P5: A(t0+2)h0 P6: A(t0+2)h1 P7: B(t1+2)h0  P8: B(t1+2)h1 + vmcnt(4)
// vmcnt(4): at P4 queue = B(t1)[4] A(t1)[4] B(t0+2)[4] -> lands B(t1)+A(t1)
// before P5 reads them; at P8 symmetric. Never 0 in steady state.
// Phase: reads; stage; [lgkmcnt(8) on 12-read phases]; barrier; lgkmcnt(0);
// setprio(1); 16 MFMA; setprio(0); barrier.
// Swizzle (T2, 0-conflict R1-R10): slot quad = quad ^ (row&7), applied to
// per-lane GLOBAL source (LDS dest linear) and to the ds_read quad; fragment
// rows have row&7 == lq&7 so qsw[kk] = ((kk*4+lr)^(lq&7))*8.
// RoPE-pair N-remap: wave wc, frag nf -> within-head d = (2*(wc&1)+(nf>>1))*16
// + (nf&1)*64 + lq, head = wc>>1. Pairs (nf=2pl, 2pl+1) give (d, d+64) in-wave.
__global__ __launch_bounds__(512, 2) void k_gemm_qkv(
    const u16* __restrict__ xb, const u16* __restrict__ wt,
    const float* __restrict__ bias, const float2* __restrict__ tab,
    u16* __restrict__ qb, u16* __restrict__ kb, u16* __restrict__ vbt)
{
  __shared__ __align__(16) u16 lsA[2][BM * BK];   // 32 KB x2
  __shared__ __align__(16) u16 lsB[2][BN * BK];   // 32 KB x2  (128 KB total)
  const int tid = threadIdx.x;            // 0..511
  const int wave = tid >> 6, lane = tid & 63;
  const int lq = lane & 15, lr = lane >> 4;
  const int wr = wave >> 2, wc = wave & 3;
  const int m0 = blockIdx.y * BM, n0 = blockIdx.x * BN;

  auto stA = [&](int t, int half) {       // one half-tile: 2 loads/thread, 16 KB
    const int kt = t * BK;
    #pragma unroll
    for (int ii = 0; ii < 2; ++ii) {
      int s = ii * 512 + tid;             // 16B slot 0..1023 within half
      int row = s >> 3, gq = (s & 7) ^ (row & 7);
      async16(xb + (size_t)(m0 + half * 128 + row) * EMB + kt + gq * 8,
              &lsA[t & 1][half * 8192 + s * 8]);
    }
  };
  auto stB = [&](int t, int half) {
    const int kt = t * BK;
    #pragma unroll
    for (int ii = 0; ii < 2; ++ii) {
      int s = ii * 512 + tid;
      int row = s >> 3, gq = (s & 7) ^ (row & 7);
      async16(wt + (size_t)(n0 + half * 128 + row) * EMB + kt + gq * 8,
              &lsB[t & 1][half * 8192 + s * 8]);
    }
  };

  f32x4 acc[8][4];
  #pragma unroll
  for (int i = 0; i < 8; ++i)
    #pragma unroll
    for (int j = 0; j < 4; ++j)
      acc[i][j] = f32x4{0.f, 0.f, 0.f, 0.f};

  // per-lane LDS read offsets (u16 units)
  int rbase[4];
  #pragma unroll
  for (int nf = 0; nf < 4; ++nf)
    rbase[nf] = ((wc >> 1) * 128 + (2 * (wc & 1) + (nf >> 1)) * 16 + (nf & 1) * 64 + lq) * BK;
  const int aRow0 = (wr * 128 + lq) * BK;
  int qsw[2];
  qsw[0] = ((0 + lr) ^ (lq & 7)) * 8;
  qsw[1] = ((4 + lr) ^ (lq & 7)) * 8;

  // prologue: A0(4) B0(4) B1(4) loads; vmcnt(4) -> A0+B0 landed, B1 in flight
  stA(0, 0); stA(0, 1); stB(0, 0); stB(0, 1); stB(1, 0); stB(1, 1);
  asm volatile("s_waitcnt vmcnt(4)" ::: "memory");
  GBAR();

  for (int ti = 0; ti < NT_K / 2; ++ti) {
    const int t0 = 2 * ti, t1 = t0 + 1;
    const bool notlast = (ti < NT_K / 2 - 1);

    #pragma unroll
    for (int hp = 0; hp < 2; ++hp) {      // hp=0: tile t0 (buf0), hp=1: t1 (buf1)
      const u16* Ap = lsA[hp];
      const u16* Bp = lsB[hp];
      bf16x8 bfr[4][2];

      #pragma unroll
      for (int q = 0; q < 4; ++q) {
        // ---- ds_read register subtile ----
        if (q == 0) {
          #pragma unroll
          for (int nf = 0; nf < 4; ++nf)
            #pragma unroll
            for (int kk = 0; kk < 2; ++kk)
              bfr[nf][kk] = *(const bf16x8*)(Bp + rbase[nf] + qsw[kk]);
        }
        bf16x8 af[2][2];
        #pragma unroll
        for (int mfl = 0; mfl < 2; ++mfl)
          #pragma unroll
          for (int kk = 0; kk < 2; ++kk)
            af[mfl][kk] = *(const bf16x8*)(Ap + aRow0 + (q * 32 + mfl * 16) * BK + qsw[kk]);

        // ---- stage one half-tile ----
        if (hp == 0) {
          if      (q == 0) stA(t1, 0);
          else if (q == 1) stA(t1, 1);
          else if (q == 2) { if (notlast) stB(t0 + 2, 0); }
          else {
            if (notlast) {
              stB(t0 + 2, 1);
              asm volatile("s_waitcnt vmcnt(4)" ::: "memory");  // lands A(t1)+B(t1)
            } else {
              asm volatile("s_waitcnt vmcnt(0)" ::: "memory");  // drain for final tile
            }
          }
        } else {
          if      (q == 0) { if (notlast) stA(t0 + 2, 0); }
          else if (q == 1) { if (notlast) stA(t0 + 2, 1); }
          else if (q == 2) { if (notlast) stB(t1 + 2, 0); }
          else {
            if (notlast) {
              stB(t1 + 2, 1);
              asm volatile("s_waitcnt vmcnt(4)" ::: "memory");  // lands tile t0+2
            }
          }
        }
        if (q == 0) asm volatile("s_waitcnt lgkmcnt(8)" ::: "memory");  // partial drain of 12-read phase

        GBAR();
        WLGKM0();
        __builtin_amdgcn_s_setprio(1);
        #pragma unroll
        for (int kk = 0; kk < 2; ++kk)
          #pragma unroll
          for (int mfl = 0; mfl < 2; ++mfl)
            #pragma unroll
            for (int nf = 0; nf < 4; ++nf)
              acc[q * 2 + mfl][nf] = __builtin_amdgcn_mfma_f32_16x16x32_bf16(
                  af[mfl][kk], bfr[nf][kk], acc[q * 2 + mfl][nf], 0, 0, 0);
        __builtin_amdgcn_s_setprio(0);
        GBAR();
      }
    }
  }

  // ---------------- epilogue (fused bias + RoPE / V-transpose) ----------------
  const int w = n0 >> 11;                  // 0=q, 1=k, 2=v (BN=256 divides 2048)
  const int h = ((n0 & 2047) >> 7) + (wc >> 1);
  float bb[4];
  int dloc[4];
  #pragma unroll
  for (int nf = 0; nf < 4; ++nf) {
    dloc[nf] = (2 * (wc & 1) + (nf >> 1)) * 16 + (nf & 1) * 64 + lq;   // d within head
    bb[nf] = bias[n0 + (wc >> 1) * 128 + dloc[nf]];
  }

  if (w == 2) {
    // V: transpose to [B,H,D,SEQP], 4 consecutive s per 8B store
    #pragma unroll
    for (int mf = 0; mf < 8; ++mf) {
      int mg0 = m0 + wr * 128 + mf * 16 + lr * 4;
      int b = mg0 >> 11, s0 = mg0 & 2047;
      #pragma unroll
      for (int nf = 0; nf < 4; ++nf) {
        int d = dloc[nf];
        ushort4 pk;
        pk.x = f2bf(acc[mf][nf][0] + bb[nf]);
        pk.y = f2bf(acc[mf][nf][1] + bb[nf]);
        pk.z = f2bf(acc[mf][nf][2] + bb[nf]);
        pk.w = f2bf(acc[mf][nf][3] + bb[nf]);
        *(ushort4*)(vbt + ((size_t)(b * NH + h) * HD + d) * SEQP + s0) = pk;
      }
    }
  } else {
    u16* basep = (w == 0) ? qb : kb;
    const float qs = (w == 0) ? 0.12751569843736827f : 1.0f;  // log2(e)/sqrt(128) into q
    #pragma unroll
    for (int mf = 0; mf < 8; ++mf)
      #pragma unroll
      for (int r = 0; r < 4; ++r) {
        int mg = m0 + wr * 128 + mf * 16 + lr * 4 + r;
        int b = mg >> 11, s = mg & 2047;
        u16* dst = basep + ((size_t)(b * NH + h) * SEQ + s) * HD;
        #pragma unroll
        for (int pl = 0; pl < 2; ++pl) {
          int d1 = (2 * (wc & 1) + pl) * 16 + lq;      // in [0,64); partner d1+64
          float c1 = acc[mf][2 * pl][r]     + bb[2 * pl];
          float c2 = acc[mf][2 * pl + 1][r] + bb[2 * pl + 1];
          float2 s1 = tab[s * HD + d1];
          float2 s2 = tab[s * HD + d1 + 64];
          dst[d1]      = f2bf((c1 * s1.x - c2 * s1.y) * qs);
          dst[d1 + 64] = f2bf((c2 * s2.x + c1 * s2.y) * qs);
        }
      }
  }
}

// ---------------- flash attention (unchanged; round-4 structure + XCD-aware remap) ----------------
__global__ __launch_bounds__(128, 2) void k_flash(
    const u16* __restrict__ qb, const u16* __restrict__ kb,
    const u16* __restrict__ vbt, float* __restrict__ out)
{
  __shared__ __align__(16) u16 lsK[2][KT * HD];   // [key][d] 16B-grp ^= key&7    (8 KB x2)
  __shared__ __align__(16) u16 lsV[2][HD * KT];   // [d][key] 16B-grp ^= (d>>1)&3 (8 KB x2)
  __shared__ __align__(16) u16 lsP[2][WQ * KT];   // per-wave [qrow][key], 8B-grp ^= row&6

  const int tid = threadIdx.x;            // 0..127
  const int wave = tid >> 6, lane = tid & 63;
  const int lq = lane & 15, lr = lane >> 4;
  const int i = blockIdx.x;               // 0..1023
  const int xcd = i & 7, j = i >> 3;      // j: 0..127
  const int bh = xcd * 4 + (j >> 5);      // 4 heads per XCD
  const int q0 = (j & 31) * QT;
  const u16* Qg = qb + ((size_t)bh * SEQ + q0 + wave * WQ) * HD;
  const u16* Kg = kb + (size_t)bh * SEQ * HD;
  const u16* Vg = vbt + (size_t)bh * HD * SEQP;

  auto stage = [&](int tile, int buf) {
    const int k0 = tile * KT;
    #pragma unroll
    for (int ii = 0; ii < 4; ++ii) {
      int c = tid + ii * 128;
      int key = c >> 4, grp = c & 15;
      async16(Kg + (size_t)(k0 + key) * HD + ((grp ^ (key & 7)) * 8), lsK[buf] + c * 8);
    }
    #pragma unroll
    for (int ii = 0; ii < 4; ++ii) {
      int c = tid + ii * 128;
      int d = c >> 2, g2 = c & 3;
      async16(Vg + (size_t)d * SEQP + k0 + ((g2 ^ ((d >> 1) & 3)) * 8), lsV[buf] + c * 8);
    }
  };

  stage(0, 0);

  bf16x8 qf[2][4];
  #pragma unroll
  for (int qq = 0; qq < 2; ++qq)
    #pragma unroll
    for (int ks = 0; ks < 4; ++ks)
      qf[qq][ks] = *(const bf16x8*)(Qg + (size_t)(qq * 16 + lq) * HD + ks * 32 + lr * 8);

  f32x4 acc_o[2][8];
  float lsum[2] = {0.f, 0.f};
  #pragma unroll
  for (int mb = 0; mb < 2; ++mb)
    #pragma unroll
    for (int nb = 0; nb < 8; ++nb) acc_o[mb][nb] = f32x4{0.f, 0.f, 0.f, 0.f};

  for (int t = 0; t < NTILE; ++t) {
    const int p = t & 1;
    __syncthreads();                 // drains stage(t); all waves done with buf 1-p
    if (t + 1 < NTILE) stage(t + 1, 1 - p);

    // S^T = K Q^T : 32 keys x 32 q-rows per wave
    f32x4 sacc[2][2];
    #pragma unroll
    for (int kbi = 0; kbi < 2; ++kbi)
      #pragma unroll
      for (int qq = 0; qq < 2; ++qq) sacc[kbi][qq] = f32x4{0.f, 0.f, 0.f, 0.f};
    #pragma unroll
    for (int ks = 0; ks < 4; ++ks) {
      bf16x8 kf[2];
      #pragma unroll
      for (int kbi = 0; kbi < 2; ++kbi) {
        int key = kbi * 16 + lq;
        int g = (ks * 4 + lr) ^ (key & 7);
        kf[kbi] = *(const bf16x8*)(lsK[p] + key * HD + g * 8);
      }
      #pragma unroll
      for (int kbi = 0; kbi < 2; ++kbi)
        #pragma unroll
        for (int qq = 0; qq < 2; ++qq)
          sacc[kbi][qq] = __builtin_amdgcn_mfma_f32_16x16x32_bf16(kf[kbi], qf[qq][ks], sacc[kbi][qq], 0, 0, 0);
    }

    // P = exp2(S) (log2e folded into q); packed b64 writes (4 consecutive keys/lane)
    #pragma unroll
    for (int kbi = 0; kbi < 2; ++kbi)
      #pragma unroll
      for (int qq = 0; qq < 2; ++qq) {
        float p0 = __builtin_amdgcn_exp2f(sacc[kbi][qq][0]);
        float p1 = __builtin_amdgcn_exp2f(sacc[kbi][qq][1]);
        float p2 = __builtin_amdgcn_exp2f(sacc[kbi][qq][2]);
        float p3 = __builtin_amdgcn_exp2f(sacc[kbi][qq][3]);
        lsum[qq] += (p0 + p1) + (p2 + p3);
        int row = qq * 16 + lq;
        int g = kbi * 4 + lr;
        int gp = g ^ (row & 6);
        uint2 pk;
        pk.x = (uint32_t)f2bf(p0) | ((uint32_t)f2bf(p1) << 16);
        pk.y = (uint32_t)f2bf(p2) | ((uint32_t)f2bf(p3) << 16);
        *(uint2*)(lsP[wave] + row * KT + gp * 4) = pk;
      }

    // O += P V
    bf16x8 ap[2];
    #pragma unroll
    for (int mb = 0; mb < 2; ++mb) {
      int row = mb * 16 + lq;
      int gp = (2 * lr) ^ (row & 6);
      ap[mb] = *(const bf16x8*)(lsP[wave] + row * KT + gp * 4);
    }
    #pragma unroll
    for (int nb = 0; nb < 8; ++nb) {
      int d = nb * 16 + lq;
      int g2 = lr ^ ((d >> 1) & 3);
      bf16x8 bv = *(const bf16x8*)(lsV[p] + d * KT + g2 * 8);
      #pragma unroll
      for (int mb = 0; mb < 2; ++mb)
        acc_o[mb][nb] = __builtin_amdgcn_mfma_f32_16x16x32_bf16(ap[mb], bv[0] == bv[0] ? bv : bv, acc_o[mb][nb], 0, 0, 0);
    }
  }

  float inv[2];
  #pragma unroll
  for (int qq = 0; qq < 2; ++qq) {
    float s = lsum[qq];
    s += __shfl_xor(s, 16);
    s += __shfl_xor(s, 32);
    inv[qq] = 1.0f / s;
  }
  const int b = bh >> 4, h = bh & 15;
  #pragma unroll
  for (int mb = 0; mb < 2; ++mb)
    #pragma unroll
    for (int r = 0; r < 4; ++r) {
      float iv = __shfl(inv[mb], lr * 4 + r);
      int row = wave * WQ + mb * 16 + lr * 4 + r;
      int sq = q0 + row;
      float* op = out + (((size_t)b * SEQ + sq) * NH + h) * HD;
      #pragma unroll
      for (int nb = 0; nb < 8; ++nb)
        op[nb * 16 + lq] = acc_o[mb][nb][r] * iv;
    }
}

// ---------------- launch ----------------

extern "C" void kernel_launch(void* const* d_in, const int* in_sizes, int n_in,
                              void* d_out, int out_size, void* d_ws, size_t ws_size,
                              hipStream_t stream) {
  (void)in_sizes; (void)n_in; (void)out_size; (void)ws_size;
  const float* x    = (const float*)d_in[0];
  const float* W    = (const float*)d_in[1];
  const float* bias = (const float*)d_in[2];
  float* out = (float*)d_out;

  char* p = (char*)d_ws;
  u16* xb  = (u16*)p;  p += (size_t)MM * EMB * 2;                     // 16.8 MB
  u16* wt  = (u16*)p;  p += (size_t)N3 * EMB * 2;                     // 25.2 MB
  u16* qb  = (u16*)p;  p += (size_t)NUM_B * NH * SEQ * HD * 2;        // 16.8 MB
  u16* kb  = (u16*)p;  p += (size_t)NUM_B * NH * SEQ * HD * 2;        // 16.8 MB
  u16* vbt = (u16*)p;  p += (size_t)NUM_B * NH * HD * SEQP * 2;       // 17.0 MB
  float2* tab = (float2*)p;                                           // 2.1 MB

  k_cvt_bf16<<<(MM * EMB / 4 + 255) / 256, 256, 0, stream>>>(x, xb, tab, MM * EMB / 4);
  k_transpose_w<<<dim3(N3 / 32, EMB / 32), dim3(32, 8), 0, stream>>>(W, wt);
  k_gemm_qkv<<<dim3(N3 / BN, MM / BM), 512, 0, stream>>>(xb, wt, bias, tab, qb, kb, vbt);
  k_flash<<<SEQ / QT * NUM_B * NH, 128, 0, stream>>>(qb, kb, vbt, out);
}

// Round 12
// 237.778 us; speedup vs baseline: 3.4029x; 1.0212x over previous
//
#include <hip/hip_runtime.h>
#include <stdint.h>

typedef unsigned short u16;
typedef __attribute__((ext_vector_type(8))) short bf16x8;   // 8 bf16 = 4 VGPRs
typedef __attribute__((ext_vector_type(4))) float f32x4;

#define NUM_B 2
#define SEQ   2048
#define SEQP  2080      // padded V row stride
#define NH    16
#define HD    128
#define EMB   2048      // NH*HD
#define N3    6144      // 3*EMB
#define MM    4096      // NUM_B*SEQ
#define QT    64        // flash q-rows per block (2 waves)
#define WQ    32        // flash q-rows per wave
#define KT    32        // flash keys per k-tile
#define NTILE (SEQ / KT)

// ---- GEMM tile params: 128x384, BK=64, 8 waves -> 512 blocks = 2.0 exact rounds ----
#define BM 128
#define BN 384
#define BK 64
#define NT_K (EMB / BK)   // 32 K-tiles, 16 iterations of 2

__device__ __forceinline__ u16 f2bf(float f) {
  union { float f; unsigned u; } c; c.f = f;
  return (u16)((c.u + 0x7FFFu + ((c.u >> 16) & 1u)) >> 16);   // RNE
}
__device__ __forceinline__ void async16(const void* g, void* l) {
  __builtin_amdgcn_global_load_lds(
      (const __attribute__((address_space(1))) void*)g,
      (__attribute__((address_space(3))) void*)l, 16, 0, 0);
}

#define GBAR()   asm volatile("s_barrier" ::: "memory")
#define WLGKM0() asm volatile("s_waitcnt lgkmcnt(0)" ::: "memory")

// ---------------- prep kernels ----------------

// bf16 cast for x, with the RoPE sincos table fused into the first 262144
// threads (saves one launch; double-precision sincos matches numpy fp32 tables)
__global__ void k_cvt_bf16(const float* __restrict__ in, u16* __restrict__ out,
                           float2* __restrict__ tab, int n4) {
  int i = blockIdx.x * blockDim.x + threadIdx.x;
  if (i >= n4) return;
  const float4 v = ((const float4*)in)[i];
  ushort4 o;
  o.x = f2bf(v.x); o.y = f2bf(v.y); o.z = f2bf(v.z); o.w = f2bf(v.w);
  ((ushort4*)out)[i] = o;
  if (i < SEQ * HD) {
    double t = (double)i;
    tab[i] = make_float2((float)cos(t), (float)sin(t));
  }
}

// W [EMB][N3] fp32 -> Wt [N3][EMB] bf16
__global__ void k_transpose_w(const float* __restrict__ W, u16* __restrict__ Wt) {
  __shared__ float t[32][33];
  int n0 = blockIdx.x * 32, k0 = blockIdx.y * 32;
  int tx = threadIdx.x, ty = threadIdx.y;
  #pragma unroll
  for (int i = ty; i < 32; i += 8)
    t[i][tx] = W[(size_t)(k0 + i) * N3 + n0 + tx];
  __syncthreads();
  #pragma unroll
  for (int i = ty; i < 32; i += 8)
    Wt[(size_t)(n0 + i) * EMB + k0 + tx] = f2bf(t[tx][i]);
}

// ---------------- QKV GEMM: 128x384, R4-style schedule, ZERO grid tail ----------------
// R11 ledger: R4 (256x256) = 134.4 us = ~42% resident eff x 0.75 rounds (384
// blocks, 1.5 rounds at 1 block/CU). Area-65536 tiles always give 384 blocks;
// an area-49152 tile gives 512 blocks = EXACTLY 2.0 rounds -> no tail. 128x384
// is the register-feasible one: 8 waves = 2M x 4N -> per-wave 64x96,
// acc[4][6]=96 AGPR (< 128 hard cap, R6/R9-proven), frags ~64 VGPR -> fits the
// 256 budget at 2 waves/SIMD. LDS = A 2x16KB + B 2x48KB = 128 KB (same as R4).
// Schedule = R4's proven pattern on 2 phases/tile (NOT R8's (kk,mh) split,
// which regressed): per tile, Ph0 reads bfr[6][2] (12 b128) + af(mf0,1) (4),
// 24 MFMA; Ph1 reads af(mf2,3) (4), 24 MFMA. Phase: reads; stage;
// [lgkmcnt(8) on Ph0]; barrier; lgkmcnt(0); setprio(1); MFMA; setprio(0);
// barrier. 4 barriers/K-tile (vs R4's 8).
// Staging (stA = 2 loads/thr = whole 16KB A tile; stB unit = 2 loads = 16KB,
// 3 units per B tile); buffers: tile t -> buf t&1.
//   Ph1(t0.0): stA(t1)            [buf1 A last read prev iter Ph4 -> safe]
//   Ph2(t0.1): stB(t0+2,u0,u1)    [buf0 B last read Ph1 -> safe]; vmcnt(4)
//   Ph3(t1.0): stA(t0+2)+stB(t0+2,u2) [buf0 A last read Ph2; B as above]
//   Ph4(t1.1): stB(t1+2,u0..2)    [buf1 B last read Ph3 -> safe]; vmcnt(6)
// vmcnt ledger (loads): prologue A0[2] B0[6] B1[6]=14, vmcnt(6) lands A0+B0.
// Steady: enter iter with 6 (B(t1)); Ph1 +2=8; Ph2 +4=12, vmcnt(4) lands
// B(t1)+A(t1) (oldest 8) before Ph3 reads them; Ph3 +4=8; Ph4 +6=14, vmcnt(6)
// lands tile t0+2 (oldest 8) before next Ph1. Last iter: Ph2 vmcnt(0). Never
// 0 in steady state.
// Swizzle (T2, 0-conflict R1-R11): slot quad = quad ^ (row&7) on per-lane
// GLOBAL source (LDS dest linear) + on ds_read quad; qsw[kk]=((kk*4+lr)^(lq&7))*8.
// N-mapping (R6-verified): pair-group pg = 3*wc + pl (pl=0..2), head j=pg>>2,
// strip s4=pg&3; nf=2*pl+half -> col = j*128 + s4*16 + half*64 + lq. Each wave
// holds both halves of its 3 RoPE pairs; q/k/v per group (H = 3*bx + j).
// Accumulation per element: t asc, kk asc -> bit-identical to R4.
__global__ __launch_bounds__(512, 2) void k_gemm_qkv(
    const u16* __restrict__ xb, const u16* __restrict__ wt,
    const float* __restrict__ bias, const float2* __restrict__ tab,
    u16* __restrict__ qb, u16* __restrict__ kb, u16* __restrict__ vbt)
{
  __shared__ __align__(16) u16 lsA[2][BM * BK];   // 16 KB x2
  __shared__ __align__(16) u16 lsB[2][BN * BK];   // 48 KB x2  (128 KB total)
  const int tid = threadIdx.x;            // 0..511
  const int wave = tid >> 6, lane = tid & 63;
  const int lq = lane & 15, lr = lane >> 4;
  const int wr = wave >> 2, wc = wave & 3;
  const int m0 = blockIdx.y * BM, n0 = blockIdx.x * BN;

  auto stA = [&](int t) {                 // whole 128x64 A tile: 2 loads/thread
    const int kt = t * BK;
    #pragma unroll
    for (int ii = 0; ii < 2; ++ii) {
      int s = ii * 512 + tid;             // 16B slot 0..1023
      int row = s >> 3, gq = (s & 7) ^ (row & 7);
      async16(xb + (size_t)(m0 + row) * EMB + kt + gq * 8, &lsA[t & 1][s * 8]);
    }
  };
  auto stB = [&](int t, int u) {          // one 128-row third: 2 loads/thread
    const int kt = t * BK;
    #pragma unroll
    for (int ii = 0; ii < 2; ++ii) {
      int s = u * 1024 + ii * 512 + tid;  // 16B slot within B tile
      int row = s >> 3, gq = (s & 7) ^ (row & 7);
      async16(wt + (size_t)(n0 + row) * EMB + kt + gq * 8, &lsB[t & 1][s * 8]);
    }
  };

  f32x4 acc[4][6];
  #pragma unroll
  for (int i = 0; i < 4; ++i)
    #pragma unroll
    for (int j = 0; j < 6; ++j)
      acc[i][j] = f32x4{0.f, 0.f, 0.f, 0.f};

  // per-lane LDS read offsets (u16 units)
  int rbase[6];
  #pragma unroll
  for (int nf = 0; nf < 6; ++nf) {
    int pg = 3 * wc + (nf >> 1);
    int col = (pg >> 2) * 128 + (pg & 3) * 16 + (nf & 1) * 64 + lq;
    rbase[nf] = col * BK;
  }
  const int aRow0 = (wr * 64 + lq) * BK;
  int qsw[2];
  qsw[0] = ((0 + lr) ^ (lq & 7)) * 8;
  qsw[1] = ((4 + lr) ^ (lq & 7)) * 8;

  // prologue: A0[2] B0[6] B1[6] = 14 loads; vmcnt(6) -> A0+B0 landed, B1 in flight
  stA(0); stB(0, 0); stB(0, 1); stB(0, 2); stB(1, 0); stB(1, 1); stB(1, 2);
  asm volatile("s_waitcnt vmcnt(6)" ::: "memory");
  GBAR();

  for (int ti = 0; ti < NT_K / 2; ++ti) {
    const int t0 = 2 * ti, t1 = t0 + 1;
    const bool nl = (ti < NT_K / 2 - 1);

    #pragma unroll
    for (int hp = 0; hp < 2; ++hp) {      // hp=0: tile t0 (buf0), hp=1: t1 (buf1)
      const u16* Ap = lsA[hp];
      const u16* Bp = lsB[hp];
      bf16x8 bfr[6][2];

      #pragma unroll
      for (int ph = 0; ph < 2; ++ph) {
        // ---- ds_read register subtile ----
        if (ph == 0) {
          #pragma unroll
          for (int nf = 0; nf < 6; ++nf)
            #pragma unroll
            for (int kk = 0; kk < 2; ++kk)
              bfr[nf][kk] = *(const bf16x8*)(Bp + rbase[nf] + qsw[kk]);
        }
        bf16x8 af[2][2];
        #pragma unroll
        for (int mfl = 0; mfl < 2; ++mfl)
          #pragma unroll
          for (int kk = 0; kk < 2; ++kk)
            af[mfl][kk] = *(const bf16x8*)(Ap + aRow0 + ((ph * 2 + mfl) * 16) * BK + qsw[kk]);

        // ---- stage schedule (R4-mirrored; hazards & vmcnt ledger in header) ----
        if (hp == 0) {
          if (ph == 0) {
            stA(t1);
          } else {
            if (nl) {
              stB(t0 + 2, 0); stB(t0 + 2, 1);
              asm volatile("s_waitcnt vmcnt(4)" ::: "memory");  // lands B(t1)+A(t1)
            } else {
              asm volatile("s_waitcnt vmcnt(0)" ::: "memory");  // drain for final tile
            }
          }
        } else {
          if (ph == 0) {
            if (nl) { stA(t0 + 2); stB(t0 + 2, 2); }
          } else {
            if (nl) {
              stB(t1 + 2, 0); stB(t1 + 2, 1); stB(t1 + 2, 2);
              asm volatile("s_waitcnt vmcnt(6)" ::: "memory");  // lands tile t0+2
            }
          }
        }
        if (ph == 0) asm volatile("s_waitcnt lgkmcnt(8)" ::: "memory");  // partial drain of 16-read phase

        GBAR();
        WLGKM0();
        __builtin_amdgcn_s_setprio(1);
        #pragma unroll
        for (int kk = 0; kk < 2; ++kk)
          #pragma unroll
          for (int mfl = 0; mfl < 2; ++mfl)
            #pragma unroll
            for (int nf = 0; nf < 6; ++nf)
              acc[ph * 2 + mfl][nf] = __builtin_amdgcn_mfma_f32_16x16x32_bf16(
                  af[mfl][kk], bfr[nf][kk], acc[ph * 2 + mfl][nf], 0, 0, 0);
        __builtin_amdgcn_s_setprio(0);
        GBAR();
      }
    }
  }

  // ---------------- epilogue (fused bias + RoPE / V-transpose, per pair-group) ----------------
  const int m0w = m0 + wr * 64;
  const int bxH = n0 >> 7;                 // = 3 * blockIdx.x
  #pragma unroll
  for (int pl = 0; pl < 3; ++pl) {
    const int pg = 3 * wc + pl;
    const int j = pg >> 2;                 // head within tile (0..2)
    const int s4 = pg & 3;                 // 16-col strip within half-head
    const int H = bxH + j;                 // absolute head index (0..47)
    const int w = H >> 4;                  // 0=q, 1=k, 2=v
    const int h = H & 15;
    const int d1 = s4 * 16 + lq;           // d within head, in [0,64); partner d1+64
    const float b1 = bias[n0 + j * 128 + d1];
    const float b2 = bias[n0 + j * 128 + d1 + 64];

    if (w == 2) {
      // V: transpose to [B,H,D,SEQP], 4 consecutive s per 8B store
      #pragma unroll
      for (int mf = 0; mf < 4; ++mf) {
        int mg0 = m0w + mf * 16 + lr * 4;
        int b = mg0 >> 11, s0 = mg0 & 2047;
        ushort4 pk;
        pk.x = f2bf(acc[mf][2 * pl][0] + b1);
        pk.y = f2bf(acc[mf][2 * pl][1] + b1);
        pk.z = f2bf(acc[mf][2 * pl][2] + b1);
        pk.w = f2bf(acc[mf][2 * pl][3] + b1);
        *(ushort4*)(vbt + ((size_t)(b * NH + h) * HD + d1) * SEQP + s0) = pk;
        pk.x = f2bf(acc[mf][2 * pl + 1][0] + b2);
        pk.y = f2bf(acc[mf][2 * pl + 1][1] + b2);
        pk.z = f2bf(acc[mf][2 * pl + 1][2] + b2);
        pk.w = f2bf(acc[mf][2 * pl + 1][3] + b2);
        *(ushort4*)(vbt + ((size_t)(b * NH + h) * HD + d1 + 64) * SEQP + s0) = pk;
      }
    } else {
      u16* basep = (w == 0) ? qb : kb;
      const float qs = (w == 0) ? 0.12751569843736827f : 1.0f;  // log2(e)/sqrt(128) into q
      #pragma unroll
      for (int mf = 0; mf < 4; ++mf)
        #pragma unroll
        for (int r = 0; r < 4; ++r) {
          int mg = m0w + mf * 16 + lr * 4 + r;
          int b = mg >> 11, s = mg & 2047;
          u16* dst = basep + ((size_t)(b * NH + h) * SEQ + s) * HD;
          float c1 = acc[mf][2 * pl][r]     + b1;
          float c2 = acc[mf][2 * pl + 1][r] + b2;
          float2 s1 = tab[s * HD + d1];
          float2 s2 = tab[s * HD + d1 + 64];
          dst[d1]      = f2bf((c1 * s1.x - c2 * s1.y) * qs);
          dst[d1 + 64] = f2bf((c2 * s2.x + c1 * s2.y) * qs);
        }
    }
  }
}

// ---------------- flash attention (round-4 structure + XCD remap; + setprio) ----------------
__global__ __launch_bounds__(128, 2) void k_flash(
    const u16* __restrict__ qb, const u16* __restrict__ kb,
    const u16* __restrict__ vbt, float* __restrict__ out)
{
  __shared__ __align__(16) u16 lsK[2][KT * HD];   // [key][d] 16B-grp ^= key&7    (8 KB x2)
  __shared__ __align__(16) u16 lsV[2][HD * KT];   // [d][key] 16B-grp ^= (d>>1)&3 (8 KB x2)
  __shared__ __align__(16) u16 lsP[2][WQ * KT];   // per-wave [qrow][key], 8B-grp ^= row&6

  const int tid = threadIdx.x;            // 0..127
  const int wave = tid >> 6, lane = tid & 63;
  const int lq = lane & 15, lr = lane >> 4;
  const int i = blockIdx.x;               // 0..1023
  const int xcd = i & 7, j = i >> 3;      // j: 0..127
  const int bh = xcd * 4 + (j >> 5);      // 4 heads per XCD
  const int q0 = (j & 31) * QT;
  const u16* Qg = qb + ((size_t)bh * SEQ + q0 + wave * WQ) * HD;
  const u16* Kg = kb + (size_t)bh * SEQ * HD;
  const u16* Vg = vbt + (size_t)bh * HD * SEQP;

  auto stage = [&](int tile, int buf) {
    const int k0 = tile * KT;
    #pragma unroll
    for (int ii = 0; ii < 4; ++ii) {
      int c = tid + ii * 128;
      int key = c >> 4, grp = c & 15;
      async16(Kg + (size_t)(k0 + key) * HD + ((grp ^ (key & 7)) * 8), lsK[buf] + c * 8);
    }
    #pragma unroll
    for (int ii = 0; ii < 4; ++ii) {
      int c = tid + ii * 128;
      int d = c >> 2, g2 = c & 3;
      async16(Vg + (size_t)d * SEQP + k0 + ((g2 ^ ((d >> 1) & 3)) * 8), lsV[buf] + c * 8);
    }
  };

  stage(0, 0);

  bf16x8 qf[2][4];
  #pragma unroll
  for (int qq = 0; qq < 2; ++qq)
    #pragma unroll
    for (int ks = 0; ks < 4; ++ks)
      qf[qq][ks] = *(const bf16x8*)(Qg + (size_t)(qq * 16 + lq) * HD + ks * 32 + lr * 8);

  f32x4 acc_o[2][8];
  float lsum[2] = {0.f, 0.f};
  #pragma unroll
  for (int mb = 0; mb < 2; ++mb)
    #pragma unroll
    for (int nb = 0; nb < 8; ++nb) acc_o[mb][nb] = f32x4{0.f, 0.f, 0.f, 0.f};

  for (int t = 0; t < NTILE; ++t) {
    const int p = t & 1;
    __syncthreads();                 // drains stage(t); all waves done with buf 1-p
    if (t + 1 < NTILE) stage(t + 1, 1 - p);

    // S^T = K Q^T : 32 keys x 32 q-rows per wave
    f32x4 sacc[2][2];
    #pragma unroll
    for (int kbi = 0; kbi < 2; ++kbi)
      #pragma unroll
      for (int qq = 0; qq < 2; ++qq) sacc[kbi][qq] = f32x4{0.f, 0.f, 0.f, 0.f};
    __builtin_amdgcn_s_setprio(1);
    #pragma unroll
    for (int ks = 0; ks < 4; ++ks) {
      bf16x8 kf[2];
      #pragma unroll
      for (int kbi = 0; kbi < 2; ++kbi) {
        int key = kbi * 16 + lq;
        int g = (ks * 4 + lr) ^ (key & 7);
        kf[kbi] = *(const bf16x8*)(lsK[p] + key * HD + g * 8);
      }
      #pragma unroll
      for (int kbi = 0; kbi < 2; ++kbi)
        #pragma unroll
        for (int qq = 0; qq < 2; ++qq)
          sacc[kbi][qq] = __builtin_amdgcn_mfma_f32_16x16x32_bf16(kf[kbi], qf[qq][ks], sacc[kbi][qq], 0, 0, 0);
    }
    __builtin_amdgcn_s_setprio(0);

    // P = exp2(S) (log2e folded into q); packed b64 writes (4 consecutive keys/lane)
    #pragma unroll
    for (int kbi = 0; kbi < 2; ++kbi)
      #pragma unroll
      for (int qq = 0; qq < 2; ++qq) {
        float p0 = __builtin_amdgcn_exp2f(sacc[kbi][qq][0]);
        float p1 = __builtin_amdgcn_exp2f(sacc[kbi][qq][1]);
        float p2 = __builtin_amdgcn_exp2f(sacc[kbi][qq][2]);
        float p3 = __builtin_amdgcn_exp2f(sacc[kbi][qq][3]);
        lsum[qq] += (p0 + p1) + (p2 + p3);
        int row = qq * 16 + lq;
        int g = kbi * 4 + lr;
        int gp = g ^ (row & 6);
        uint2 pk;
        pk.x = (uint32_t)f2bf(p0) | ((uint32_t)f2bf(p1) << 16);
        pk.y = (uint32_t)f2bf(p2) | ((uint32_t)f2bf(p3) << 16);
        *(uint2*)(lsP[wave] + row * KT + gp * 4) = pk;
      }

    // O += P V
    bf16x8 ap[2];
    #pragma unroll
    for (int mb = 0; mb < 2; ++mb) {
      int row = mb * 16 + lq;
      int gp = (2 * lr) ^ (row & 6);
      ap[mb] = *(const bf16x8*)(lsP[wave] + row * KT + gp * 4);
    }
    __builtin_amdgcn_s_setprio(1);
    #pragma unroll
    for (int nb = 0; nb < 8; ++nb) {
      int d = nb * 16 + lq;
      int g2 = lr ^ ((d >> 1) & 3);
      bf16x8 bv = *(const bf16x8*)(lsV[p] + d * KT + g2 * 8);
      #pragma unroll
      for (int mb = 0; mb < 2; ++mb)
        acc_o[mb][nb] = __builtin_amdgcn_mfma_f32_16x16x32_bf16(ap[mb], bv[0] == bv[0] ? bv : bv, acc_o[mb][nb], 0, 0, 0);
    }
    __builtin_amdgcn_s_setprio(0);
  }

  float inv[2];
  #pragma unroll
  for (int qq = 0; qq < 2; ++qq) {
    float s = lsum[qq];
    s += __shfl_xor(s, 16);
    s += __shfl_xor(s, 32);
    inv[qq] = 1.0f / s;
  }
  const int b = bh >> 4, h = bh & 15;
  #pragma unroll
  for (int mb = 0; mb < 2; ++mb)
    #pragma unroll
    for (int r = 0; r < 4; ++r) {
      float iv = __shfl(inv[mb], lr * 4 + r);
      int row = wave * WQ + mb * 16 + lr * 4 + r;
      int sq = q0 + row;
      float* op = out + (((size_t)b * SEQ + sq) * NH + h) * HD;
      #pragma unroll
      for (int nb = 0; nb < 8; ++nb)
        op[nb * 16 + lq] = acc_o[mb][nb][r] * iv;
    }
}

// ---------------- launch ----------------

extern "C" void kernel_launch(void* const* d_in, const int* in_sizes, int n_in,
                              void* d_out, int out_size, void* d_ws, size_t ws_size,
                              hipStream_t stream) {
  (void)in_sizes; (void)n_in; (void)out_size; (void)ws_size;
  const float* x    = (const float*)d_in[0];
  const float* W    = (const float*)d_in[1];
  const float* bias = (const float*)d_in[2];
  float* out = (float*)d_out;

  char* p = (char*)d_ws;
  u16* xb  = (u16*)p;  p += (size_t)MM * EMB * 2;                     // 16.8 MB
  u16* wt  = (u16*)p;  p += (size_t)N3 * EMB * 2;                     // 25.2 MB
  u16* qb  = (u16*)p;  p += (size_t)NUM_B * NH * SEQ * HD * 2;        // 16.8 MB
  u16* kb  = (u16*)p;  p += (size_t)NUM_B * NH * SEQ * HD * 2;        // 16.8 MB
  u16* vbt = (u16*)p;  p += (size_t)NUM_B * NH * HD * SEQP * 2;       // 17.0 MB
  float2* tab = (float2*)p;                                           // 2.1 MB

  k_cvt_bf16<<<(MM * EMB / 4 + 255) / 256, 256, 0, stream>>>(x, xb, tab, MM * EMB / 4);
  k_transpose_w<<<dim3(N3 / 32, EMB / 32), dim3(32, 8), 0, stream>>>(W, wt);
  k_gemm_qkv<<<dim3(N3 / BN, MM / BM), 512, 0, stream>>>(xb, wt, bias, tab, qb, kb, vbt);
  k_flash<<<SEQ / QT * NUM_B * NH, 128, 0, stream>>>(qb, kb, vbt, out);
}

// Round 13
// 231.656 us; speedup vs baseline: 3.4929x; 1.0264x over previous
//
#include <hip/hip_runtime.h>
#include <stdint.h>

typedef unsigned short u16;
typedef __attribute__((ext_vector_type(8))) short bf16x8;   // 8 bf16 = 4 VGPRs
typedef __attribute__((ext_vector_type(4))) float f32x4;

#define NUM_B 2
#define SEQ   2048
#define SEQP  2080      // padded V row stride
#define NH    16
#define HD    128
#define EMB   2048      // NH*HD
#define N3    6144      // 3*EMB
#define MM    4096      // NUM_B*SEQ
#define QT    128       // flash q-rows per block (4 waves) -- R13: was 64
#define WQ    32        // flash q-rows per wave
#define KT    32        // flash keys per k-tile
#define NTILE (SEQ / KT)

// ---- GEMM tile params: 128x384, BK=64, 8 waves -> 512 blocks = 2.0 exact rounds ----
#define BM 128
#define BN 384
#define BK 64
#define NT_K (EMB / BK)   // 32 K-tiles, 16 iterations of 2

__device__ __forceinline__ u16 f2bf(float f) {
  union { float f; unsigned u; } c; c.f = f;
  return (u16)((c.u + 0x7FFFu + ((c.u >> 16) & 1u)) >> 16);   // RNE
}
__device__ __forceinline__ void async16(const void* g, void* l) {
  __builtin_amdgcn_global_load_lds(
      (const __attribute__((address_space(1))) void*)g,
      (__attribute__((address_space(3))) void*)l, 16, 0, 0);
}

#define GBAR()   asm volatile("s_barrier" ::: "memory")
#define WLGKM0() asm volatile("s_waitcnt lgkmcnt(0)" ::: "memory")

// ---------------- prep kernels ----------------

// bf16 cast for x, with the RoPE sincos table fused into the first 262144
// threads (saves one launch; double-precision sincos matches numpy fp32 tables)
__global__ void k_cvt_bf16(const float* __restrict__ in, u16* __restrict__ out,
                           float2* __restrict__ tab, int n4) {
  int i = blockIdx.x * blockDim.x + threadIdx.x;
  if (i >= n4) return;
  const float4 v = ((const float4*)in)[i];
  ushort4 o;
  o.x = f2bf(v.x); o.y = f2bf(v.y); o.z = f2bf(v.z); o.w = f2bf(v.w);
  ((ushort4*)out)[i] = o;
  if (i < SEQ * HD) {
    double t = (double)i;
    tab[i] = make_float2((float)cos(t), (float)sin(t));
  }
}

// W [EMB][N3] fp32 -> Wt [N3][EMB] bf16
__global__ void k_transpose_w(const float* __restrict__ W, u16* __restrict__ Wt) {
  __shared__ float t[32][33];
  int n0 = blockIdx.x * 32, k0 = blockIdx.y * 32;
  int tx = threadIdx.x, ty = threadIdx.y;
  #pragma unroll
  for (int i = ty; i < 32; i += 8)
    t[i][tx] = W[(size_t)(k0 + i) * N3 + n0 + tx];
  __syncthreads();
  #pragma unroll
  for (int i = ty; i < 32; i += 8)
    Wt[(size_t)(n0 + i) * EMB + k0 + tx] = f2bf(t[tx][i]);
}

// ---------------- QKV GEMM: 128x384, R4-style schedule, ZERO grid tail ----------------
// (R12 best: 131.3 us, MfmaUtil 32.2, no spill. UNCHANGED this round.)
// 8 waves = 2M x 4N -> per-wave 64x96, acc[4][6]=96 AGPR; LDS 128 KB;
// 512 blocks = exactly 2.0 rounds at 1 block/CU. Per tile: Ph0 reads
// bfr[6][2] (12 b128) + af(mf0,1) (4), 24 MFMA; Ph1 reads af(mf2,3) (4),
// 24 MFMA. Staging (buf = t&1): Ph1 stA(t1); Ph2 stB(t0+2,u0,u1)+vmcnt(4);
// Ph3 stA(t0+2)+stB(t0+2,u2); Ph4 stB(t1+2,u0..2)+vmcnt(6). vmcnt ledger in
// R12 notes; never 0 in steady state. Swizzle: quad ^= row&7 on global src +
// ds_read quad (0-conflict R1-R12). N-mapping: pg = 3*wc+pl, head j = pg>>2,
// col = j*128 + (pg&3)*16 + half*64 + lq; q/k/v per group (H = 3*bx + j).
__global__ __launch_bounds__(512, 2) void k_gemm_qkv(
    const u16* __restrict__ xb, const u16* __restrict__ wt,
    const float* __restrict__ bias, const float2* __restrict__ tab,
    u16* __restrict__ qb, u16* __restrict__ kb, u16* __restrict__ vbt)
{
  __shared__ __align__(16) u16 lsA[2][BM * BK];   // 16 KB x2
  __shared__ __align__(16) u16 lsB[2][BN * BK];   // 48 KB x2  (128 KB total)
  const int tid = threadIdx.x;            // 0..511
  const int wave = tid >> 6, lane = tid & 63;
  const int lq = lane & 15, lr = lane >> 4;
  const int wr = wave >> 2, wc = wave & 3;
  const int m0 = blockIdx.y * BM, n0 = blockIdx.x * BN;

  auto stA = [&](int t) {                 // whole 128x64 A tile: 2 loads/thread
    const int kt = t * BK;
    #pragma unroll
    for (int ii = 0; ii < 2; ++ii) {
      int s = ii * 512 + tid;             // 16B slot 0..1023
      int row = s >> 3, gq = (s & 7) ^ (row & 7);
      async16(xb + (size_t)(m0 + row) * EMB + kt + gq * 8, &lsA[t & 1][s * 8]);
    }
  };
  auto stB = [&](int t, int u) {          // one 128-row third: 2 loads/thread
    const int kt = t * BK;
    #pragma unroll
    for (int ii = 0; ii < 2; ++ii) {
      int s = u * 1024 + ii * 512 + tid;  // 16B slot within B tile
      int row = s >> 3, gq = (s & 7) ^ (row & 7);
      async16(wt + (size_t)(n0 + row) * EMB + kt + gq * 8, &lsB[t & 1][s * 8]);
    }
  };

  f32x4 acc[4][6];
  #pragma unroll
  for (int i = 0; i < 4; ++i)
    #pragma unroll
    for (int j = 0; j < 6; ++j)
      acc[i][j] = f32x4{0.f, 0.f, 0.f, 0.f};

  // per-lane LDS read offsets (u16 units)
  int rbase[6];
  #pragma unroll
  for (int nf = 0; nf < 6; ++nf) {
    int pg = 3 * wc + (nf >> 1);
    int col = (pg >> 2) * 128 + (pg & 3) * 16 + (nf & 1) * 64 + lq;
    rbase[nf] = col * BK;
  }
  const int aRow0 = (wr * 64 + lq) * BK;
  int qsw[2];
  qsw[0] = ((0 + lr) ^ (lq & 7)) * 8;
  qsw[1] = ((4 + lr) ^ (lq & 7)) * 8;

  // prologue: A0[2] B0[6] B1[6] = 14 loads; vmcnt(6) -> A0+B0 landed, B1 in flight
  stA(0); stB(0, 0); stB(0, 1); stB(0, 2); stB(1, 0); stB(1, 1); stB(1, 2);
  asm volatile("s_waitcnt vmcnt(6)" ::: "memory");
  GBAR();

  for (int ti = 0; ti < NT_K / 2; ++ti) {
    const int t0 = 2 * ti, t1 = t0 + 1;
    const bool nl = (ti < NT_K / 2 - 1);

    #pragma unroll
    for (int hp = 0; hp < 2; ++hp) {      // hp=0: tile t0 (buf0), hp=1: t1 (buf1)
      const u16* Ap = lsA[hp];
      const u16* Bp = lsB[hp];
      bf16x8 bfr[6][2];

      #pragma unroll
      for (int ph = 0; ph < 2; ++ph) {
        // ---- ds_read register subtile ----
        if (ph == 0) {
          #pragma unroll
          for (int nf = 0; nf < 6; ++nf)
            #pragma unroll
            for (int kk = 0; kk < 2; ++kk)
              bfr[nf][kk] = *(const bf16x8*)(Bp + rbase[nf] + qsw[kk]);
        }
        bf16x8 af[2][2];
        #pragma unroll
        for (int mfl = 0; mfl < 2; ++mfl)
          #pragma unroll
          for (int kk = 0; kk < 2; ++kk)
            af[mfl][kk] = *(const bf16x8*)(Ap + aRow0 + ((ph * 2 + mfl) * 16) * BK + qsw[kk]);

        // ---- stage schedule (R4-mirrored; hazards & vmcnt ledger in header) ----
        if (hp == 0) {
          if (ph == 0) {
            stA(t1);
          } else {
            if (nl) {
              stB(t0 + 2, 0); stB(t0 + 2, 1);
              asm volatile("s_waitcnt vmcnt(4)" ::: "memory");  // lands B(t1)+A(t1)
            } else {
              asm volatile("s_waitcnt vmcnt(0)" ::: "memory");  // drain for final tile
            }
          }
        } else {
          if (ph == 0) {
            if (nl) { stA(t0 + 2); stB(t0 + 2, 2); }
          } else {
            if (nl) {
              stB(t1 + 2, 0); stB(t1 + 2, 1); stB(t1 + 2, 2);
              asm volatile("s_waitcnt vmcnt(6)" ::: "memory");  // lands tile t0+2
            }
          }
        }
        if (ph == 0) asm volatile("s_waitcnt lgkmcnt(8)" ::: "memory");  // partial drain of 16-read phase

        GBAR();
        WLGKM0();
        __builtin_amdgcn_s_setprio(1);
        #pragma unroll
        for (int kk = 0; kk < 2; ++kk)
          #pragma unroll
          for (int mfl = 0; mfl < 2; ++mfl)
            #pragma unroll
            for (int nf = 0; nf < 6; ++nf)
              acc[ph * 2 + mfl][nf] = __builtin_amdgcn_mfma_f32_16x16x32_bf16(
                  af[mfl][kk], bfr[nf][kk], acc[ph * 2 + mfl][nf], 0, 0, 0);
        __builtin_amdgcn_s_setprio(0);
        GBAR();
      }
    }
  }

  // ---------------- epilogue (fused bias + RoPE / V-transpose, per pair-group) ----------------
  const int m0w = m0 + wr * 64;
  const int bxH = n0 >> 7;                 // = 3 * blockIdx.x
  #pragma unroll
  for (int pl = 0; pl < 3; ++pl) {
    const int pg = 3 * wc + pl;
    const int j = pg >> 2;                 // head within tile (0..2)
    const int s4 = pg & 3;                 // 16-col strip within half-head
    const int H = bxH + j;                 // absolute head index (0..47)
    const int w = H >> 4;                  // 0=q, 1=k, 2=v
    const int h = H & 15;
    const int d1 = s4 * 16 + lq;           // d within head, in [0,64); partner d1+64
    const float b1 = bias[n0 + j * 128 + d1];
    const float b2 = bias[n0 + j * 128 + d1 + 64];

    if (w == 2) {
      // V: transpose to [B,H,D,SEQP], 4 consecutive s per 8B store
      #pragma unroll
      for (int mf = 0; mf < 4; ++mf) {
        int mg0 = m0w + mf * 16 + lr * 4;
        int b = mg0 >> 11, s0 = mg0 & 2047;
        ushort4 pk;
        pk.x = f2bf(acc[mf][2 * pl][0] + b1);
        pk.y = f2bf(acc[mf][2 * pl][1] + b1);
        pk.z = f2bf(acc[mf][2 * pl][2] + b1);
        pk.w = f2bf(acc[mf][2 * pl][3] + b1);
        *(ushort4*)(vbt + ((size_t)(b * NH + h) * HD + d1) * SEQP + s0) = pk;
        pk.x = f2bf(acc[mf][2 * pl + 1][0] + b2);
        pk.y = f2bf(acc[mf][2 * pl + 1][1] + b2);
        pk.z = f2bf(acc[mf][2 * pl + 1][2] + b2);
        pk.w = f2bf(acc[mf][2 * pl + 1][3] + b2);
        *(ushort4*)(vbt + ((size_t)(b * NH + h) * HD + d1 + 64) * SEQP + s0) = pk;
      }
    } else {
      u16* basep = (w == 0) ? qb : kb;
      const float qs = (w == 0) ? 0.12751569843736827f : 1.0f;  // log2(e)/sqrt(128) into q
      #pragma unroll
      for (int mf = 0; mf < 4; ++mf)
        #pragma unroll
        for (int r = 0; r < 4; ++r) {
          int mg = m0w + mf * 16 + lr * 4 + r;
          int b = mg >> 11, s = mg & 2047;
          u16* dst = basep + ((size_t)(b * NH + h) * SEQ + s) * HD;
          float c1 = acc[mf][2 * pl][r]     + b1;
          float c2 = acc[mf][2 * pl + 1][r] + b2;
          float2 s1 = tab[s * HD + d1];
          float2 s2 = tab[s * HD + d1 + 64];
          dst[d1]      = f2bf((c1 * s1.x - c2 * s1.y) * qs);
          dst[d1 + 64] = f2bf((c2 * s2.x + c1 * s2.y) * qs);
        }
    }
  }
}

// ---------------- flash attention: QT=128 (4 waves, 512 blocks) ----------------
// R13: each K/V panel now staged by 16 blocks (was 32) -> half the chip-wide
// async-LDS staging traffic and L2 re-reads at identical per-wave MFMA work.
// 512 blocks = 8 XCDs x 4 heads x 16 q-blocks (bijective); per XCD the 4-head
// K/V working set (4 MB) matches L2. LDS padded to 54 KB (> 160/3) to hard-cap
// occupancy at 2 blocks/CU (8 waves/CU, same as before) against dispatch skew.
// Per-wave compute, swizzles, numerics, and output indexing unchanged.
#define VPAD 3584
__global__ __launch_bounds__(256, 2) void k_flash(
    const u16* __restrict__ qb, const u16* __restrict__ kb,
    const u16* __restrict__ vbt, float* __restrict__ out)
{
  __shared__ __align__(16) u16 lsK[2][KT * HD];          // [key][d] 16B-grp ^= key&7    (8 KB x2)
  __shared__ __align__(16) u16 lsV[2][HD * KT + VPAD];   // [d][key] 16B-grp ^= (d>>1)&3 (8+7 KB x2)
  __shared__ __align__(16) u16 lsP[4][WQ * KT];          // per-wave [qrow][key], 8B-grp ^= row&6

  const int tid = threadIdx.x;            // 0..255
  const int wave = tid >> 6, lane = tid & 63;
  const int lq = lane & 15, lr = lane >> 4;
  const int i = blockIdx.x;               // 0..511
  const int xcd = i & 7, j = i >> 3;      // j: 0..63
  const int bh = xcd * 4 + (j >> 4);      // 4 heads per XCD
  const int q0 = (j & 15) * QT;
  const u16* Qg = qb + ((size_t)bh * SEQ + q0 + wave * WQ) * HD;
  const u16* Kg = kb + (size_t)bh * SEQ * HD;
  const u16* Vg = vbt + (size_t)bh * HD * SEQP;

  auto stage = [&](int tile, int buf) {
    const int k0 = tile * KT;
    #pragma unroll
    for (int ii = 0; ii < 2; ++ii) {
      int c = tid + ii * 256;             // 0..511 (8 KB K tile)
      int key = c >> 4, grp = c & 15;
      async16(Kg + (size_t)(k0 + key) * HD + ((grp ^ (key & 7)) * 8), lsK[buf] + c * 8);
    }
    #pragma unroll
    for (int ii = 0; ii < 2; ++ii) {
      int c = tid + ii * 256;             // 0..511 (8 KB V tile)
      int d = c >> 2, g2 = c & 3;
      async16(Vg + (size_t)d * SEQP + k0 + ((g2 ^ ((d >> 1) & 3)) * 8), lsV[buf] + c * 8);
    }
  };

  stage(0, 0);

  bf16x8 qf[2][4];
  #pragma unroll
  for (int qq = 0; qq < 2; ++qq)
    #pragma unroll
    for (int ks = 0; ks < 4; ++ks)
      qf[qq][ks] = *(const bf16x8*)(Qg + (size_t)(qq * 16 + lq) * HD + ks * 32 + lr * 8);

  f32x4 acc_o[2][8];
  float lsum[2] = {0.f, 0.f};
  #pragma unroll
  for (int mb = 0; mb < 2; ++mb)
    #pragma unroll
    for (int nb = 0; nb < 8; ++nb) acc_o[mb][nb] = f32x4{0.f, 0.f, 0.f, 0.f};

  for (int t = 0; t < NTILE; ++t) {
    const int p = t & 1;
    __syncthreads();                 // drains stage(t); all waves done with buf 1-p
    if (t + 1 < NTILE) stage(t + 1, 1 - p);

    // S^T = K Q^T : 32 keys x 32 q-rows per wave
    f32x4 sacc[2][2];
    #pragma unroll
    for (int kbi = 0; kbi < 2; ++kbi)
      #pragma unroll
      for (int qq = 0; qq < 2; ++qq) sacc[kbi][qq] = f32x4{0.f, 0.f, 0.f, 0.f};
    __builtin_amdgcn_s_setprio(1);
    #pragma unroll
    for (int ks = 0; ks < 4; ++ks) {
      bf16x8 kf[2];
      #pragma unroll
      for (int kbi = 0; kbi < 2; ++kbi) {
        int key = kbi * 16 + lq;
        int g = (ks * 4 + lr) ^ (key & 7);
        kf[kbi] = *(const bf16x8*)(lsK[p] + key * HD + g * 8);
      }
      #pragma unroll
      for (int kbi = 0; kbi < 2; ++kbi)
        #pragma unroll
        for (int qq = 0; qq < 2; ++qq)
          sacc[kbi][qq] = __builtin_amdgcn_mfma_f32_16x16x32_bf16(kf[kbi], qf[qq][ks], sacc[kbi][qq], 0, 0, 0);
    }
    __builtin_amdgcn_s_setprio(0);

    // P = exp2(S) (log2e folded into q); packed b64 writes (4 consecutive keys/lane)
    #pragma unroll
    for (int kbi = 0; kbi < 2; ++kbi)
      #pragma unroll
      for (int qq = 0; qq < 2; ++qq) {
        float p0 = __builtin_amdgcn_exp2f(sacc[kbi][qq][0]);
        float p1 = __builtin_amdgcn_exp2f(sacc[kbi][qq][1]);
        float p2 = __builtin_amdgcn_exp2f(sacc[kbi][qq][2]);
        float p3 = __builtin_amdgcn_exp2f(sacc[kbi][qq][3]);
        lsum[qq] += (p0 + p1) + (p2 + p3);
        int row = qq * 16 + lq;
        int g = kbi * 4 + lr;
        int gp = g ^ (row & 6);
        uint2 pk;
        pk.x = (uint32_t)f2bf(p0) | ((uint32_t)f2bf(p1) << 16);
        pk.y = (uint32_t)f2bf(p2) | ((uint32_t)f2bf(p3) << 16);
        *(uint2*)(lsP[wave] + row * KT + gp * 4) = pk;
      }

    // O += P V
    bf16x8 ap[2];
    #pragma unroll
    for (int mb = 0; mb < 2; ++mb) {
      int row = mb * 16 + lq;
      int gp = (2 * lr) ^ (row & 6);
      ap[mb] = *(const bf16x8*)(lsP[wave] + row * KT + gp * 4);
    }
    __builtin_amdgcn_s_setprio(1);
    #pragma unroll
    for (int nb = 0; nb < 8; ++nb) {
      int d = nb * 16 + lq;
      int g2 = lr ^ ((d >> 1) & 3);
      bf16x8 bv = *(const bf16x8*)(lsV[p] + d * KT + g2 * 8);
      #pragma unroll
      for (int mb = 0; mb < 2; ++mb)
        acc_o[mb][nb] = __builtin_amdgcn_mfma_f32_16x16x32_bf16(ap[mb], bv[0] == bv[0] ? bv : bv, acc_o[mb][nb], 0, 0, 0);
    }
    __builtin_amdgcn_s_setprio(0);
  }

  float inv[2];
  #pragma unroll
  for (int qq = 0; qq < 2; ++qq) {
    float s = lsum[qq];
    s += __shfl_xor(s, 16);
    s += __shfl_xor(s, 32);
    inv[qq] = 1.0f / s;
  }
  const int b = bh >> 4, h = bh & 15;
  #pragma unroll
  for (int mb = 0; mb < 2; ++mb)
    #pragma unroll
    for (int r = 0; r < 4; ++r) {
      float iv = __shfl(inv[mb], lr * 4 + r);
      int row = wave * WQ + mb * 16 + lr * 4 + r;
      int sq = q0 + row;
      float* op = out + (((size_t)b * SEQ + sq) * NH + h) * HD;
      #pragma unroll
      for (int nb = 0; nb < 8; ++nb)
        op[nb * 16 + lq] = acc_o[mb][nb][r] * iv;
    }
}

// ---------------- launch ----------------

extern "C" void kernel_launch(void* const* d_in, const int* in_sizes, int n_in,
                              void* d_out, int out_size, void* d_ws, size_t ws_size,
                              hipStream_t stream) {
  (void)in_sizes; (void)n_in; (void)out_size; (void)ws_size;
  const float* x    = (const float*)d_in[0];
  const float* W    = (const float*)d_in[1];
  const float* bias = (const float*)d_in[2];
  float* out = (float*)d_out;

  char* p = (char*)d_ws;
  u16* xb  = (u16*)p;  p += (size_t)MM * EMB * 2;                     // 16.8 MB
  u16* wt  = (u16*)p;  p += (size_t)N3 * EMB * 2;                     // 25.2 MB
  u16* qb  = (u16*)p;  p += (size_t)NUM_B * NH * SEQ * HD * 2;        // 16.8 MB
  u16* kb  = (u16*)p;  p += (size_t)NUM_B * NH * SEQ * HD * 2;        // 16.8 MB
  u16* vbt = (u16*)p;  p += (size_t)NUM_B * NH * HD * SEQP * 2;       // 17.0 MB
  float2* tab = (float2*)p;                                           // 2.1 MB

  k_cvt_bf16<<<(MM * EMB / 4 + 255) / 256, 256, 0, stream>>>(x, xb, tab, MM * EMB / 4);
  k_transpose_w<<<dim3(N3 / 32, EMB / 32), dim3(32, 8), 0, stream>>>(W, wt);
  k_gemm_qkv<<<dim3(N3 / BN, MM / BM), 512, 0, stream>>>(xb, wt, bias, tab, qb, kb, vbt);
  k_flash<<<SEQ / QT * NUM_B * NH, 256, 0, stream>>>(qb, kb, vbt, out);
}

// Round 14
// 230.576 us; speedup vs baseline: 3.5092x; 1.0047x over previous
//
#include <hip/hip_runtime.h>
#include <stdint.h>

typedef unsigned short u16;
typedef __attribute__((ext_vector_type(8))) short bf16x8;   // 8 bf16 = 4 VGPRs
typedef __attribute__((ext_vector_type(4))) float f32x4;

#define NUM_B 2
#define SEQ   2048
#define SEQP  2080      // padded V row stride
#define NH    16
#define HD    128
#define EMB   2048      // NH*HD
#define N3    6144      // 3*EMB
#define MM    4096      // NUM_B*SEQ
#define QT    256       // flash q-rows per block (8 waves) -- R14: was 128
#define WQ    32        // flash q-rows per wave
#define KT    32        // flash keys per k-tile
#define NTILE (SEQ / KT)

// ---- GEMM tile params: 128x384, BK=64, 8 waves -> 512 blocks = 2.0 exact rounds ----
#define BM 128
#define BN 384
#define BK 64
#define NT_K (EMB / BK)   // 32 K-tiles, 16 iterations of 2

__device__ __forceinline__ u16 f2bf(float f) {
  union { float f; unsigned u; } c; c.f = f;
  return (u16)((c.u + 0x7FFFu + ((c.u >> 16) & 1u)) >> 16);   // RNE
}
__device__ __forceinline__ void async16(const void* g, void* l) {
  __builtin_amdgcn_global_load_lds(
      (const __attribute__((address_space(1))) void*)g,
      (__attribute__((address_space(3))) void*)l, 16, 0, 0);
}

#define GBAR()   asm volatile("s_barrier" ::: "memory")
#define WLGKM0() asm volatile("s_waitcnt lgkmcnt(0)" ::: "memory")

// ---------------- prep: fused bf16-cast (+sincos table) and W-transpose ----------------
// One launch, branch on blockIdx (wave-uniform): blocks [0,8192) do the x cast
// (first 1024 also fill the RoPE table), blocks [8192, 20480) do the 32x32
// tiled W transpose (thread shape flattened 256 -> 32x8). Both parts are
// memory-bound; merging overlaps their tails and saves one launch gap.
#define CVT_BLKS (MM * EMB / 4 / 256)          // 8192
#define TRN_BX   (N3 / 32)                     // 192
__global__ void k_prep(const float* __restrict__ x, u16* __restrict__ xb,
                       float2* __restrict__ tab,
                       const float* __restrict__ W, u16* __restrict__ Wt) {
  __shared__ float t[32][33];
  const int bid = blockIdx.x;
  if (bid < CVT_BLKS) {
    int i = bid * 256 + threadIdx.x;
    const float4 v = ((const float4*)x)[i];
    ushort4 o;
    o.x = f2bf(v.x); o.y = f2bf(v.y); o.z = f2bf(v.z); o.w = f2bf(v.w);
    ((ushort4*)xb)[i] = o;
    if (i < SEQ * HD) {
      double tt = (double)i;
      tab[i] = make_float2((float)cos(tt), (float)sin(tt));
    }
  } else {
    int b2 = bid - CVT_BLKS;
    int n0 = (b2 % TRN_BX) * 32, k0 = (b2 / TRN_BX) * 32;
    int tx = threadIdx.x & 31, ty = threadIdx.x >> 5;   // 32 x 8
    #pragma unroll
    for (int i = ty; i < 32; i += 8)
      t[i][tx] = W[(size_t)(k0 + i) * N3 + n0 + tx];
    __syncthreads();
    #pragma unroll
    for (int i = ty; i < 32; i += 8)
      Wt[(size_t)(n0 + i) * EMB + k0 + tx] = f2bf(t[tx][i]);
  }
}

// ---------------- QKV GEMM: 128x384, R4-style schedule, ZERO grid tail ----------------
// (R12/R13 best: ~131 us, MfmaUtil 32.4, no spill. UNCHANGED this round.)
// 8 waves = 2M x 4N -> per-wave 64x96, acc[4][6]=96 AGPR; LDS 128 KB;
// 512 blocks = exactly 2.0 rounds at 1 block/CU. Per tile: Ph0 reads
// bfr[6][2] (12 b128) + af(mf0,1) (4), 24 MFMA; Ph1 reads af(mf2,3) (4),
// 24 MFMA. Staging (buf = t&1): Ph1 stA(t1); Ph2 stB(t0+2,u0,u1)+vmcnt(4);
// Ph3 stA(t0+2)+stB(t0+2,u2); Ph4 stB(t1+2,u0..2)+vmcnt(6). vmcnt ledger in
// R12 notes; never 0 in steady state. Swizzle: quad ^= row&7 on global src +
// ds_read quad (0-conflict R1-R13). N-mapping: pg = 3*wc+pl, head j = pg>>2,
// col = j*128 + (pg&3)*16 + half*64 + lq; q/k/v per group (H = 3*bx + j).
__global__ __launch_bounds__(512, 2) void k_gemm_qkv(
    const u16* __restrict__ xb, const u16* __restrict__ wt,
    const float* __restrict__ bias, const float2* __restrict__ tab,
    u16* __restrict__ qb, u16* __restrict__ kb, u16* __restrict__ vbt)
{
  __shared__ __align__(16) u16 lsA[2][BM * BK];   // 16 KB x2
  __shared__ __align__(16) u16 lsB[2][BN * BK];   // 48 KB x2  (128 KB total)
  const int tid = threadIdx.x;            // 0..511
  const int wave = tid >> 6, lane = tid & 63;
  const int lq = lane & 15, lr = lane >> 4;
  const int wr = wave >> 2, wc = wave & 3;
  const int m0 = blockIdx.y * BM, n0 = blockIdx.x * BN;

  auto stA = [&](int t) {                 // whole 128x64 A tile: 2 loads/thread
    const int kt = t * BK;
    #pragma unroll
    for (int ii = 0; ii < 2; ++ii) {
      int s = ii * 512 + tid;             // 16B slot 0..1023
      int row = s >> 3, gq = (s & 7) ^ (row & 7);
      async16(xb + (size_t)(m0 + row) * EMB + kt + gq * 8, &lsA[t & 1][s * 8]);
    }
  };
  auto stB = [&](int t, int u) {          // one 128-row third: 2 loads/thread
    const int kt = t * BK;
    #pragma unroll
    for (int ii = 0; ii < 2; ++ii) {
      int s = u * 1024 + ii * 512 + tid;  // 16B slot within B tile
      int row = s >> 3, gq = (s & 7) ^ (row & 7);
      async16(wt + (size_t)(n0 + row) * EMB + kt + gq * 8, &lsB[t & 1][s * 8]);
    }
  };

  f32x4 acc[4][6];
  #pragma unroll
  for (int i = 0; i < 4; ++i)
    #pragma unroll
    for (int j = 0; j < 6; ++j)
      acc[i][j] = f32x4{0.f, 0.f, 0.f, 0.f};

  // per-lane LDS read offsets (u16 units)
  int rbase[6];
  #pragma unroll
  for (int nf = 0; nf < 6; ++nf) {
    int pg = 3 * wc + (nf >> 1);
    int col = (pg >> 2) * 128 + (pg & 3) * 16 + (nf & 1) * 64 + lq;
    rbase[nf] = col * BK;
  }
  const int aRow0 = (wr * 64 + lq) * BK;
  int qsw[2];
  qsw[0] = ((0 + lr) ^ (lq & 7)) * 8;
  qsw[1] = ((4 + lr) ^ (lq & 7)) * 8;

  // prologue: A0[2] B0[6] B1[6] = 14 loads; vmcnt(6) -> A0+B0 landed, B1 in flight
  stA(0); stB(0, 0); stB(0, 1); stB(0, 2); stB(1, 0); stB(1, 1); stB(1, 2);
  asm volatile("s_waitcnt vmcnt(6)" ::: "memory");
  GBAR();

  for (int ti = 0; ti < NT_K / 2; ++ti) {
    const int t0 = 2 * ti, t1 = t0 + 1;
    const bool nl = (ti < NT_K / 2 - 1);

    #pragma unroll
    for (int hp = 0; hp < 2; ++hp) {      // hp=0: tile t0 (buf0), hp=1: t1 (buf1)
      const u16* Ap = lsA[hp];
      const u16* Bp = lsB[hp];
      bf16x8 bfr[6][2];

      #pragma unroll
      for (int ph = 0; ph < 2; ++ph) {
        // ---- ds_read register subtile ----
        if (ph == 0) {
          #pragma unroll
          for (int nf = 0; nf < 6; ++nf)
            #pragma unroll
            for (int kk = 0; kk < 2; ++kk)
              bfr[nf][kk] = *(const bf16x8*)(Bp + rbase[nf] + qsw[kk]);
        }
        bf16x8 af[2][2];
        #pragma unroll
        for (int mfl = 0; mfl < 2; ++mfl)
          #pragma unroll
          for (int kk = 0; kk < 2; ++kk)
            af[mfl][kk] = *(const bf16x8*)(Ap + aRow0 + ((ph * 2 + mfl) * 16) * BK + qsw[kk]);

        // ---- stage schedule (R4-mirrored; hazards & vmcnt ledger in header) ----
        if (hp == 0) {
          if (ph == 0) {
            stA(t1);
          } else {
            if (nl) {
              stB(t0 + 2, 0); stB(t0 + 2, 1);
              asm volatile("s_waitcnt vmcnt(4)" ::: "memory");  // lands B(t1)+A(t1)
            } else {
              asm volatile("s_waitcnt vmcnt(0)" ::: "memory");  // drain for final tile
            }
          }
        } else {
          if (ph == 0) {
            if (nl) { stA(t0 + 2); stB(t0 + 2, 2); }
          } else {
            if (nl) {
              stB(t1 + 2, 0); stB(t1 + 2, 1); stB(t1 + 2, 2);
              asm volatile("s_waitcnt vmcnt(6)" ::: "memory");  // lands tile t0+2
            }
          }
        }
        if (ph == 0) asm volatile("s_waitcnt lgkmcnt(8)" ::: "memory");  // partial drain of 16-read phase

        GBAR();
        WLGKM0();
        __builtin_amdgcn_s_setprio(1);
        #pragma unroll
        for (int kk = 0; kk < 2; ++kk)
          #pragma unroll
          for (int mfl = 0; mfl < 2; ++mfl)
            #pragma unroll
            for (int nf = 0; nf < 6; ++nf)
              acc[ph * 2 + mfl][nf] = __builtin_amdgcn_mfma_f32_16x16x32_bf16(
                  af[mfl][kk], bfr[nf][kk], acc[ph * 2 + mfl][nf], 0, 0, 0);
        __builtin_amdgcn_s_setprio(0);
        GBAR();
      }
    }
  }

  // ---------------- epilogue (fused bias + RoPE / V-transpose, per pair-group) ----------------
  const int m0w = m0 + wr * 64;
  const int bxH = n0 >> 7;                 // = 3 * blockIdx.x
  #pragma unroll
  for (int pl = 0; pl < 3; ++pl) {
    const int pg = 3 * wc + pl;
    const int j = pg >> 2;                 // head within tile (0..2)
    const int s4 = pg & 3;                 // 16-col strip within half-head
    const int H = bxH + j;                 // absolute head index (0..47)
    const int w = H >> 4;                  // 0=q, 1=k, 2=v
    const int h = H & 15;
    const int d1 = s4 * 16 + lq;           // d within head, in [0,64); partner d1+64
    const float b1 = bias[n0 + j * 128 + d1];
    const float b2 = bias[n0 + j * 128 + d1 + 64];

    if (w == 2) {
      // V: transpose to [B,H,D,SEQP], 4 consecutive s per 8B store
      #pragma unroll
      for (int mf = 0; mf < 4; ++mf) {
        int mg0 = m0w + mf * 16 + lr * 4;
        int b = mg0 >> 11, s0 = mg0 & 2047;
        ushort4 pk;
        pk.x = f2bf(acc[mf][2 * pl][0] + b1);
        pk.y = f2bf(acc[mf][2 * pl][1] + b1);
        pk.z = f2bf(acc[mf][2 * pl][2] + b1);
        pk.w = f2bf(acc[mf][2 * pl][3] + b1);
        *(ushort4*)(vbt + ((size_t)(b * NH + h) * HD + d1) * SEQP + s0) = pk;
        pk.x = f2bf(acc[mf][2 * pl + 1][0] + b2);
        pk.y = f2bf(acc[mf][2 * pl + 1][1] + b2);
        pk.z = f2bf(acc[mf][2 * pl + 1][2] + b2);
        pk.w = f2bf(acc[mf][2 * pl + 1][3] + b2);
        *(ushort4*)(vbt + ((size_t)(b * NH + h) * HD + d1 + 64) * SEQP + s0) = pk;
      }
    } else {
      u16* basep = (w == 0) ? qb : kb;
      const float qs = (w == 0) ? 0.12751569843736827f : 1.0f;  // log2(e)/sqrt(128) into q
      #pragma unroll
      for (int mf = 0; mf < 4; ++mf)
        #pragma unroll
        for (int r = 0; r < 4; ++r) {
          int mg = m0w + mf * 16 + lr * 4 + r;
          int b = mg >> 11, s = mg & 2047;
          u16* dst = basep + ((size_t)(b * NH + h) * SEQ + s) * HD;
          float c1 = acc[mf][2 * pl][r]     + b1;
          float c2 = acc[mf][2 * pl + 1][r] + b2;
          float2 s1 = tab[s * HD + d1];
          float2 s2 = tab[s * HD + d1 + 64];
          dst[d1]      = f2bf((c1 * s1.x - c2 * s1.y) * qs);
          dst[d1 + 64] = f2bf((c2 * s2.x + c1 * s2.y) * qs);
        }
    }
  }
}

// ---------------- flash attention: QT=256 (8 waves, 256 blocks = 1/CU) ----------------
// R14: each K/V panel now staged by 8 blocks (was 16) -> per-CU staging
// traffic halves again (16 KB/tile vs 32) at identical per-CU MFMA work
// (8 waves/CU = 2/SIMD, same as R13's 2 blocks x 4 waves). 256 blocks =
// 8 XCDs x 4 heads x 8 q-blocks (bijective); per-XCD 4-head K/V working set
// = 4 MB = L2. LDS 48 KB (no pad needed at 1 block/CU). Per-wave compute,
// swizzles, numerics, and output indexing unchanged.
__global__ __launch_bounds__(512, 1) void k_flash(
    const u16* __restrict__ qb, const u16* __restrict__ kb,
    const u16* __restrict__ vbt, float* __restrict__ out)
{
  __shared__ __align__(16) u16 lsK[2][KT * HD];   // [key][d] 16B-grp ^= key&7    (8 KB x2)
  __shared__ __align__(16) u16 lsV[2][HD * KT];   // [d][key] 16B-grp ^= (d>>1)&3 (8 KB x2)
  __shared__ __align__(16) u16 lsP[8][WQ * KT];   // per-wave [qrow][key], 8B-grp ^= row&6

  const int tid = threadIdx.x;            // 0..511
  const int wave = tid >> 6, lane = tid & 63;
  const int lq = lane & 15, lr = lane >> 4;
  const int i = blockIdx.x;               // 0..255
  const int xcd = i & 7, j = i >> 3;      // j: 0..31
  const int bh = xcd * 4 + (j >> 3);      // 4 heads per XCD
  const int q0 = (j & 7) * QT;
  const u16* Qg = qb + ((size_t)bh * SEQ + q0 + wave * WQ) * HD;
  const u16* Kg = kb + (size_t)bh * SEQ * HD;
  const u16* Vg = vbt + (size_t)bh * HD * SEQP;

  auto stage = [&](int tile, int buf) {
    const int k0 = tile * KT;
    {
      int c = tid;                        // 0..511 (8 KB K tile, 1 load/thread)
      int key = c >> 4, grp = c & 15;
      async16(Kg + (size_t)(k0 + key) * HD + ((grp ^ (key & 7)) * 8), lsK[buf] + c * 8);
    }
    {
      int c = tid;                        // 0..511 (8 KB V tile, 1 load/thread)
      int d = c >> 2, g2 = c & 3;
      async16(Vg + (size_t)d * SEQP + k0 + ((g2 ^ ((d >> 1) & 3)) * 8), lsV[buf] + c * 8);
    }
  };

  stage(0, 0);

  bf16x8 qf[2][4];
  #pragma unroll
  for (int qq = 0; qq < 2; ++qq)
    #pragma unroll
    for (int ks = 0; ks < 4; ++ks)
      qf[qq][ks] = *(const bf16x8*)(Qg + (size_t)(qq * 16 + lq) * HD + ks * 32 + lr * 8);

  f32x4 acc_o[2][8];
  float lsum[2] = {0.f, 0.f};
  #pragma unroll
  for (int mb = 0; mb < 2; ++mb)
    #pragma unroll
    for (int nb = 0; nb < 8; ++nb) acc_o[mb][nb] = f32x4{0.f, 0.f, 0.f, 0.f};

  for (int t = 0; t < NTILE; ++t) {
    const int p = t & 1;
    __syncthreads();                 // drains stage(t); all waves done with buf 1-p
    if (t + 1 < NTILE) stage(t + 1, 1 - p);

    // S^T = K Q^T : 32 keys x 32 q-rows per wave
    f32x4 sacc[2][2];
    #pragma unroll
    for (int kbi = 0; kbi < 2; ++kbi)
      #pragma unroll
      for (int qq = 0; qq < 2; ++qq) sacc[kbi][qq] = f32x4{0.f, 0.f, 0.f, 0.f};
    __builtin_amdgcn_s_setprio(1);
    #pragma unroll
    for (int ks = 0; ks < 4; ++ks) {
      bf16x8 kf[2];
      #pragma unroll
      for (int kbi = 0; kbi < 2; ++kbi) {
        int key = kbi * 16 + lq;
        int g = (ks * 4 + lr) ^ (key & 7);
        kf[kbi] = *(const bf16x8*)(lsK[p] + key * HD + g * 8);
      }
      #pragma unroll
      for (int kbi = 0; kbi < 2; ++kbi)
        #pragma unroll
        for (int qq = 0; qq < 2; ++qq)
          sacc[kbi][qq] = __builtin_amdgcn_mfma_f32_16x16x32_bf16(kf[kbi], qf[qq][ks], sacc[kbi][qq], 0, 0, 0);
    }
    __builtin_amdgcn_s_setprio(0);

    // P = exp2(S) (log2e folded into q); packed b64 writes (4 consecutive keys/lane)
    #pragma unroll
    for (int kbi = 0; kbi < 2; ++kbi)
      #pragma unroll
      for (int qq = 0; qq < 2; ++qq) {
        float p0 = __builtin_amdgcn_exp2f(sacc[kbi][qq][0]);
        float p1 = __builtin_amdgcn_exp2f(sacc[kbi][qq][1]);
        float p2 = __builtin_amdgcn_exp2f(sacc[kbi][qq][2]);
        float p3 = __builtin_amdgcn_exp2f(sacc[kbi][qq][3]);
        lsum[qq] += (p0 + p1) + (p2 + p3);
        int row = qq * 16 + lq;
        int g = kbi * 4 + lr;
        int gp = g ^ (row & 6);
        uint2 pk;
        pk.x = (uint32_t)f2bf(p0) | ((uint32_t)f2bf(p1) << 16);
        pk.y = (uint32_t)f2bf(p2) | ((uint32_t)f2bf(p3) << 16);
        *(uint2*)(lsP[wave] + row * KT + gp * 4) = pk;
      }

    // O += P V
    bf16x8 ap[2];
    #pragma unroll
    for (int mb = 0; mb < 2; ++mb) {
      int row = mb * 16 + lq;
      int gp = (2 * lr) ^ (row & 6);
      ap[mb] = *(const bf16x8*)(lsP[wave] + row * KT + gp * 4);
    }
    __builtin_amdgcn_s_setprio(1);
    #pragma unroll
    for (int nb = 0; nb < 8; ++nb) {
      int d = nb * 16 + lq;
      int g2 = lr ^ ((d >> 1) & 3);
      bf16x8 bv = *(const bf16x8*)(lsV[p] + d * KT + g2 * 8);
      #pragma unroll
      for (int mb = 0; mb < 2; ++mb)
        acc_o[mb][nb] = __builtin_amdgcn_mfma_f32_16x16x32_bf16(ap[mb], bv[0] == bv[0] ? bv : bv, acc_o[mb][nb], 0, 0, 0);
    }
    __builtin_amdgcn_s_setprio(0);
  }

  float inv[2];
  #pragma unroll
  for (int qq = 0; qq < 2; ++qq) {
    float s = lsum[qq];
    s += __shfl_xor(s, 16);
    s += __shfl_xor(s, 32);
    inv[qq] = 1.0f / s;
  }
  const int b = bh >> 4, h = bh & 15;
  #pragma unroll
  for (int mb = 0; mb < 2; ++mb)
    #pragma unroll
    for (int r = 0; r < 4; ++r) {
      float iv = __shfl(inv[mb], lr * 4 + r);
      int row = wave * WQ + mb * 16 + lr * 4 + r;
      int sq = q0 + row;
      float* op = out + (((size_t)b * SEQ + sq) * NH + h) * HD;
      #pragma unroll
      for (int nb = 0; nb < 8; ++nb)
        op[nb * 16 + lq] = acc_o[mb][nb][r] * iv;
    }
}

// ---------------- launch ----------------

extern "C" void kernel_launch(void* const* d_in, const int* in_sizes, int n_in,
                              void* d_out, int out_size, void* d_ws, size_t ws_size,
                              hipStream_t stream) {
  (void)in_sizes; (void)n_in; (void)out_size; (void)ws_size;
  const float* x    = (const float*)d_in[0];
  const float* W    = (const float*)d_in[1];
  const float* bias = (const float*)d_in[2];
  float* out = (float*)d_out;

  char* p = (char*)d_ws;
  u16* xb  = (u16*)p;  p += (size_t)MM * EMB * 2;                     // 16.8 MB
  u16* wt  = (u16*)p;  p += (size_t)N3 * EMB * 2;                     // 25.2 MB
  u16* qb  = (u16*)p;  p += (size_t)NUM_B * NH * SEQ * HD * 2;        // 16.8 MB
  u16* kb  = (u16*)p;  p += (size_t)NUM_B * NH * SEQ * HD * 2;        // 16.8 MB
  u16* vbt = (u16*)p;  p += (size_t)NUM_B * NH * HD * SEQP * 2;       // 17.0 MB
  float2* tab = (float2*)p;                                           // 2.1 MB

  k_prep<<<CVT_BLKS + TRN_BX * (EMB / 32), 256, 0, stream>>>(x, xb, tab, W, wt);
  k_gemm_qkv<<<dim3(N3 / BN, MM / BM), 512, 0, stream>>>(xb, wt, bias, tab, qb, kb, vbt);
  k_flash<<<SEQ / QT * NUM_B * NH, 512, 0, stream>>>(qb, kb, vbt, out);
}

// Round 15
// 224.787 us; speedup vs baseline: 3.5996x; 1.0258x over previous
//
#include <hip/hip_runtime.h>
#include <stdint.h>

typedef unsigned short u16;
typedef __attribute__((ext_vector_type(8))) short bf16x8;   // 8 bf16 = 4 VGPRs
typedef __attribute__((ext_vector_type(4))) float f32x4;

#define NUM_B 2
#define SEQ   2048
#define SEQP  2080      // padded V row stride
#define NH    16
#define HD    128
#define EMB   2048      // NH*HD
#define N3    6144      // 3*EMB
#define MM    4096      // NUM_B*SEQ
#define QT    256       // flash q-rows per block (8 waves)
#define WQ    32        // flash q-rows per wave
#define KT    64        // flash keys per k-tile -- R15: was 32 (halves barrier count)
#define NTILE (SEQ / KT)

// ---- GEMM tile params: 128x384, BK=64, 8 waves -> 512 blocks = 2.0 exact rounds ----
#define BM 128
#define BN 384
#define BK 64
#define NT_K (EMB / BK)   // 32 K-tiles, 16 iterations of 2

__device__ __forceinline__ u16 f2bf(float f) {
  union { float f; unsigned u; } c; c.f = f;
  return (u16)((c.u + 0x7FFFu + ((c.u >> 16) & 1u)) >> 16);   // RNE
}
__device__ __forceinline__ void async16(const void* g, void* l) {
  __builtin_amdgcn_global_load_lds(
      (const __attribute__((address_space(1))) void*)g,
      (__attribute__((address_space(3))) void*)l, 16, 0, 0);
}

#define GBAR()   asm volatile("s_barrier" ::: "memory")
#define WLGKM0() asm volatile("s_waitcnt lgkmcnt(0)" ::: "memory")

// ---------------- prep: fused bf16-cast (+sincos table) and W-transpose ----------------
#define CVT_BLKS (MM * EMB / 4 / 256)          // 8192
#define TRN_BX   (N3 / 32)                     // 192
__global__ void k_prep(const float* __restrict__ x, u16* __restrict__ xb,
                       float2* __restrict__ tab,
                       const float* __restrict__ W, u16* __restrict__ Wt) {
  __shared__ float t[32][33];
  const int bid = blockIdx.x;
  if (bid < CVT_BLKS) {
    int i = bid * 256 + threadIdx.x;
    const float4 v = ((const float4*)x)[i];
    ushort4 o;
    o.x = f2bf(v.x); o.y = f2bf(v.y); o.z = f2bf(v.z); o.w = f2bf(v.w);
    ((ushort4*)xb)[i] = o;
    if (i < SEQ * HD) {
      double tt = (double)i;
      tab[i] = make_float2((float)cos(tt), (float)sin(tt));
    }
  } else {
    int b2 = bid - CVT_BLKS;
    int n0 = (b2 % TRN_BX) * 32, k0 = (b2 / TRN_BX) * 32;
    int tx = threadIdx.x & 31, ty = threadIdx.x >> 5;   // 32 x 8
    #pragma unroll
    for (int i = ty; i < 32; i += 8)
      t[i][tx] = W[(size_t)(k0 + i) * N3 + n0 + tx];
    __syncthreads();
    #pragma unroll
    for (int i = ty; i < 32; i += 8)
      Wt[(size_t)(n0 + i) * EMB + k0 + tx] = f2bf(t[tx][i]);
  }
}

// ---------------- QKV GEMM: 128x384, R4-style schedule, ZERO grid tail ----------------
// (R12-R14 best: ~131 us, MfmaUtil 32.4, no spill. UNCHANGED this round.)
__global__ __launch_bounds__(512, 2) void k_gemm_qkv(
    const u16* __restrict__ xb, const u16* __restrict__ wt,
    const float* __restrict__ bias, const float2* __restrict__ tab,
    u16* __restrict__ qb, u16* __restrict__ kb, u16* __restrict__ vbt)
{
  __shared__ __align__(16) u16 lsA[2][BM * BK];   // 16 KB x2
  __shared__ __align__(16) u16 lsB[2][BN * BK];   // 48 KB x2  (128 KB total)
  const int tid = threadIdx.x;            // 0..511
  const int wave = tid >> 6, lane = tid & 63;
  const int lq = lane & 15, lr = lane >> 4;
  const int wr = wave >> 2, wc = wave & 3;
  const int m0 = blockIdx.y * BM, n0 = blockIdx.x * BN;

  auto stA = [&](int t) {                 // whole 128x64 A tile: 2 loads/thread
    const int kt = t * BK;
    #pragma unroll
    for (int ii = 0; ii < 2; ++ii) {
      int s = ii * 512 + tid;             // 16B slot 0..1023
      int row = s >> 3, gq = (s & 7) ^ (row & 7);
      async16(xb + (size_t)(m0 + row) * EMB + kt + gq * 8, &lsA[t & 1][s * 8]);
    }
  };
  auto stB = [&](int t, int u) {          // one 128-row third: 2 loads/thread
    const int kt = t * BK;
    #pragma unroll
    for (int ii = 0; ii < 2; ++ii) {
      int s = u * 1024 + ii * 512 + tid;  // 16B slot within B tile
      int row = s >> 3, gq = (s & 7) ^ (row & 7);
      async16(wt + (size_t)(n0 + row) * EMB + kt + gq * 8, &lsB[t & 1][s * 8]);
    }
  };

  f32x4 acc[4][6];
  #pragma unroll
  for (int i = 0; i < 4; ++i)
    #pragma unroll
    for (int j = 0; j < 6; ++j)
      acc[i][j] = f32x4{0.f, 0.f, 0.f, 0.f};

  // per-lane LDS read offsets (u16 units)
  int rbase[6];
  #pragma unroll
  for (int nf = 0; nf < 6; ++nf) {
    int pg = 3 * wc + (nf >> 1);
    int col = (pg >> 2) * 128 + (pg & 3) * 16 + (nf & 1) * 64 + lq;
    rbase[nf] = col * BK;
  }
  const int aRow0 = (wr * 64 + lq) * BK;
  int qsw[2];
  qsw[0] = ((0 + lr) ^ (lq & 7)) * 8;
  qsw[1] = ((4 + lr) ^ (lq & 7)) * 8;

  // prologue: A0[2] B0[6] B1[6] = 14 loads; vmcnt(6) -> A0+B0 landed, B1 in flight
  stA(0); stB(0, 0); stB(0, 1); stB(0, 2); stB(1, 0); stB(1, 1); stB(1, 2);
  asm volatile("s_waitcnt vmcnt(6)" ::: "memory");
  GBAR();

  for (int ti = 0; ti < NT_K / 2; ++ti) {
    const int t0 = 2 * ti, t1 = t0 + 1;
    const bool nl = (ti < NT_K / 2 - 1);

    #pragma unroll
    for (int hp = 0; hp < 2; ++hp) {      // hp=0: tile t0 (buf0), hp=1: t1 (buf1)
      const u16* Ap = lsA[hp];
      const u16* Bp = lsB[hp];
      bf16x8 bfr[6][2];

      #pragma unroll
      for (int ph = 0; ph < 2; ++ph) {
        // ---- ds_read register subtile ----
        if (ph == 0) {
          #pragma unroll
          for (int nf = 0; nf < 6; ++nf)
            #pragma unroll
            for (int kk = 0; kk < 2; ++kk)
              bfr[nf][kk] = *(const bf16x8*)(Bp + rbase[nf] + qsw[kk]);
        }
        bf16x8 af[2][2];
        #pragma unroll
        for (int mfl = 0; mfl < 2; ++mfl)
          #pragma unroll
          for (int kk = 0; kk < 2; ++kk)
            af[mfl][kk] = *(const bf16x8*)(Ap + aRow0 + ((ph * 2 + mfl) * 16) * BK + qsw[kk]);

        // ---- stage schedule (R4-mirrored; hazards & vmcnt ledger in R12 notes) ----
        if (hp == 0) {
          if (ph == 0) {
            stA(t1);
          } else {
            if (nl) {
              stB(t0 + 2, 0); stB(t0 + 2, 1);
              asm volatile("s_waitcnt vmcnt(4)" ::: "memory");  // lands B(t1)+A(t1)
            } else {
              asm volatile("s_waitcnt vmcnt(0)" ::: "memory");  // drain for final tile
            }
          }
        } else {
          if (ph == 0) {
            if (nl) { stA(t0 + 2); stB(t0 + 2, 2); }
          } else {
            if (nl) {
              stB(t1 + 2, 0); stB(t1 + 2, 1); stB(t1 + 2, 2);
              asm volatile("s_waitcnt vmcnt(6)" ::: "memory");  // lands tile t0+2
            }
          }
        }
        if (ph == 0) asm volatile("s_waitcnt lgkmcnt(8)" ::: "memory");  // partial drain of 16-read phase

        GBAR();
        WLGKM0();
        __builtin_amdgcn_s_setprio(1);
        #pragma unroll
        for (int kk = 0; kk < 2; ++kk)
          #pragma unroll
          for (int mfl = 0; mfl < 2; ++mfl)
            #pragma unroll
            for (int nf = 0; nf < 6; ++nf)
              acc[ph * 2 + mfl][nf] = __builtin_amdgcn_mfma_f32_16x16x32_bf16(
                  af[mfl][kk], bfr[nf][kk], acc[ph * 2 + mfl][nf], 0, 0, 0);
        __builtin_amdgcn_s_setprio(0);
        GBAR();
      }
    }
  }

  // ---------------- epilogue (fused bias + RoPE / V-transpose, per pair-group) ----------------
  const int m0w = m0 + wr * 64;
  const int bxH = n0 >> 7;                 // = 3 * blockIdx.x
  #pragma unroll
  for (int pl = 0; pl < 3; ++pl) {
    const int pg = 3 * wc + pl;
    const int j = pg >> 2;                 // head within tile (0..2)
    const int s4 = pg & 3;                 // 16-col strip within half-head
    const int H = bxH + j;                 // absolute head index (0..47)
    const int w = H >> 4;                  // 0=q, 1=k, 2=v
    const int h = H & 15;
    const int d1 = s4 * 16 + lq;           // d within head, in [0,64); partner d1+64
    const float b1 = bias[n0 + j * 128 + d1];
    const float b2 = bias[n0 + j * 128 + d1 + 64];

    if (w == 2) {
      // V: transpose to [B,H,D,SEQP], 4 consecutive s per 8B store
      #pragma unroll
      for (int mf = 0; mf < 4; ++mf) {
        int mg0 = m0w + mf * 16 + lr * 4;
        int b = mg0 >> 11, s0 = mg0 & 2047;
        ushort4 pk;
        pk.x = f2bf(acc[mf][2 * pl][0] + b1);
        pk.y = f2bf(acc[mf][2 * pl][1] + b1);
        pk.z = f2bf(acc[mf][2 * pl][2] + b1);
        pk.w = f2bf(acc[mf][2 * pl][3] + b1);
        *(ushort4*)(vbt + ((size_t)(b * NH + h) * HD + d1) * SEQP + s0) = pk;
        pk.x = f2bf(acc[mf][2 * pl + 1][0] + b2);
        pk.y = f2bf(acc[mf][2 * pl + 1][1] + b2);
        pk.z = f2bf(acc[mf][2 * pl + 1][2] + b2);
        pk.w = f2bf(acc[mf][2 * pl + 1][3] + b2);
        *(ushort4*)(vbt + ((size_t)(b * NH + h) * HD + d1 + 64) * SEQP + s0) = pk;
      }
    } else {
      u16* basep = (w == 0) ? qb : kb;
      const float qs = (w == 0) ? 0.12751569843736827f : 1.0f;  // log2(e)/sqrt(128) into q
      #pragma unroll
      for (int mf = 0; mf < 4; ++mf)
        #pragma unroll
        for (int r = 0; r < 4; ++r) {
          int mg = m0w + mf * 16 + lr * 4 + r;
          int b = mg >> 11, s = mg & 2047;
          u16* dst = basep + ((size_t)(b * NH + h) * SEQ + s) * HD;
          float c1 = acc[mf][2 * pl][r]     + b1;
          float c2 = acc[mf][2 * pl + 1][r] + b2;
          float2 s1 = tab[s * HD + d1];
          float2 s2 = tab[s * HD + d1 + 64];
          dst[d1]      = f2bf((c1 * s1.x - c2 * s1.y) * qs);
          dst[d1 + 64] = f2bf((c2 * s2.x + c1 * s2.y) * qs);
        }
    }
  }
}

// ---------------- flash attention: QT=256, KT=64 (32 tiles, half the barriers) ----------------
// R15: per-tile overhead (barrier vmcnt-drain + wave skew + serial exp/pack)
// measured ~0.64 us/tile at KT=32 (1.16 total vs 0.52 MFMA floor). KT=64
// halves tile count; per-tile work doubles (64 MFMA/wave, kbi 0..3, 2-slot
// PV). Staging total unchanged (4 loads/thread/tile, half the tiles).
// LDS: lsK 2x16KB + lsV 2x16KB + lsP 8x4KB = 96 KB, 1 block/CU.
// Swizzles (all <=2-way, free): K rows 256B unchanged (g ^= key&7);
// V rows now 128B, 8 quads: q8 = (ks2*4+lr) ^ ((d>>1)&7), staged with the
// same involution on the global source; P rows 128B, 16 8B-groups:
// gp = g ^ (row&6) ^ ((row&8)>>1) (even XOR keeps 16B read-pairs adjacent;
// same formula on write and read). Accumulation order per output element and
// lsum add order are identical to two consecutive KT=32 tiles -> bit-identical.
__global__ __launch_bounds__(512, 1) void k_flash(
    const u16* __restrict__ qb, const u16* __restrict__ kb,
    const u16* __restrict__ vbt, float* __restrict__ out)
{
  __shared__ __align__(16) u16 lsK[2][KT * HD];   // [key][d]  16 KB x2
  __shared__ __align__(16) u16 lsV[2][HD * KT];   // [d][key]  16 KB x2
  __shared__ __align__(16) u16 lsP[8][WQ * KT];   // per-wave [qrow][key], 4 KB x8

  const int tid = threadIdx.x;            // 0..511
  const int wave = tid >> 6, lane = tid & 63;
  const int lq = lane & 15, lr = lane >> 4;
  const int i = blockIdx.x;               // 0..255
  const int xcd = i & 7, j = i >> 3;      // j: 0..31
  const int bh = xcd * 4 + (j >> 3);      // 4 heads per XCD
  const int q0 = (j & 7) * QT;
  const u16* Qg = qb + ((size_t)bh * SEQ + q0 + wave * WQ) * HD;
  const u16* Kg = kb + (size_t)bh * SEQ * HD;
  const u16* Vg = vbt + (size_t)bh * HD * SEQP;

  auto stage = [&](int tile, int buf) {
    const int k0 = tile * KT;
    #pragma unroll
    for (int ii = 0; ii < 2; ++ii) {
      int c = tid + ii * 512;             // 0..1023 (16 KB K tile)
      int key = c >> 4, grp = c & 15;
      async16(Kg + (size_t)(k0 + key) * HD + ((grp ^ (key & 7)) * 8), lsK[buf] + c * 8);
    }
    #pragma unroll
    for (int ii = 0; ii < 2; ++ii) {
      int c = tid + ii * 512;             // 0..1023 (16 KB V tile)
      int d = c >> 3, g2 = c & 7;
      async16(Vg + (size_t)d * SEQP + k0 + ((g2 ^ ((d >> 1) & 7)) * 8), lsV[buf] + c * 8);
    }
  };

  stage(0, 0);

  bf16x8 qf[2][4];
  #pragma unroll
  for (int qq = 0; qq < 2; ++qq)
    #pragma unroll
    for (int ks = 0; ks < 4; ++ks)
      qf[qq][ks] = *(const bf16x8*)(Qg + (size_t)(qq * 16 + lq) * HD + ks * 32 + lr * 8);

  f32x4 acc_o[2][8];
  float lsum[2] = {0.f, 0.f};
  #pragma unroll
  for (int mb = 0; mb < 2; ++mb)
    #pragma unroll
    for (int nb = 0; nb < 8; ++nb) acc_o[mb][nb] = f32x4{0.f, 0.f, 0.f, 0.f};

  for (int t = 0; t < NTILE; ++t) {
    const int p = t & 1;
    __syncthreads();                 // drains stage(t); all waves done with buf 1-p
    if (t + 1 < NTILE) stage(t + 1, 1 - p);

    // S^T = K Q^T : 64 keys x 32 q-rows per wave
    f32x4 sacc[4][2];
    #pragma unroll
    for (int kbi = 0; kbi < 4; ++kbi)
      #pragma unroll
      for (int qq = 0; qq < 2; ++qq) sacc[kbi][qq] = f32x4{0.f, 0.f, 0.f, 0.f};
    __builtin_amdgcn_s_setprio(1);
    #pragma unroll
    for (int ks = 0; ks < 4; ++ks) {
      bf16x8 kf[4];
      #pragma unroll
      for (int kbi = 0; kbi < 4; ++kbi) {
        int key = kbi * 16 + lq;
        int g = (ks * 4 + lr) ^ (key & 7);
        kf[kbi] = *(const bf16x8*)(lsK[p] + key * HD + g * 8);
      }
      #pragma unroll
      for (int kbi = 0; kbi < 4; ++kbi)
        #pragma unroll
        for (int qq = 0; qq < 2; ++qq)
          sacc[kbi][qq] = __builtin_amdgcn_mfma_f32_16x16x32_bf16(kf[kbi], qf[qq][ks], sacc[kbi][qq], 0, 0, 0);
    }
    __builtin_amdgcn_s_setprio(0);

    // P = exp2(S) (log2e folded into q); packed b64 writes (4 consecutive keys/lane)
    #pragma unroll
    for (int kbi = 0; kbi < 4; ++kbi)
      #pragma unroll
      for (int qq = 0; qq < 2; ++qq) {
        float p0 = __builtin_amdgcn_exp2f(sacc[kbi][qq][0]);
        float p1 = __builtin_amdgcn_exp2f(sacc[kbi][qq][1]);
        float p2 = __builtin_amdgcn_exp2f(sacc[kbi][qq][2]);
        float p3 = __builtin_amdgcn_exp2f(sacc[kbi][qq][3]);
        lsum[qq] += (p0 + p1) + (p2 + p3);
        int row = qq * 16 + lq;
        int g = kbi * 4 + lr;                        // 0..15 (8B groups in 128B row)
        int gp = g ^ (row & 6) ^ ((row & 8) >> 1);
        uint2 pk;
        pk.x = (uint32_t)f2bf(p0) | ((uint32_t)f2bf(p1) << 16);
        pk.y = (uint32_t)f2bf(p2) | ((uint32_t)f2bf(p3) << 16);
        *(uint2*)(lsP[wave] + row * KT + gp * 4) = pk;
      }

    // O += P V  (two 32-key slots)
    bf16x8 ap[2][2];
    #pragma unroll
    for (int mb = 0; mb < 2; ++mb) {
      int row = mb * 16 + lq;
      int sw = (row & 6) ^ ((row & 8) >> 1);
      #pragma unroll
      for (int ks2 = 0; ks2 < 2; ++ks2) {
        int gb = (ks2 * 8 + 2 * lr) ^ sw;            // even -> 16B-aligned
        ap[mb][ks2] = *(const bf16x8*)(lsP[wave] + row * KT + gb * 4);
      }
    }
    __builtin_amdgcn_s_setprio(1);
    #pragma unroll
    for (int nb = 0; nb < 8; ++nb) {
      int d = nb * 16 + lq;
      #pragma unroll
      for (int ks2 = 0; ks2 < 2; ++ks2) {
        int q8 = (ks2 * 4 + lr) ^ ((d >> 1) & 7);
        bf16x8 bv = *(const bf16x8*)(lsV[p] + d * KT + q8 * 8);
        #pragma unroll
        for (int mb = 0; mb < 2; ++mb)
          acc_o[mb][nb] = __builtin_amdgcn_mfma_f32_16x16x32_bf16(ap[mb][ks2], bv, acc_o[mb][nb], 0, 0, 0);
      }
    }
    __builtin_amdgcn_s_setprio(0);
  }

  float inv[2];
  #pragma unroll
  for (int qq = 0; qq < 2; ++qq) {
    float s = lsum[qq];
    s += __shfl_xor(s, 16);
    s += __shfl_xor(s, 32);
    inv[qq] = 1.0f / s;
  }
  const int b = bh >> 4, h = bh & 15;
  #pragma unroll
  for (int mb = 0; mb < 2; ++mb)
    #pragma unroll
    for (int r = 0; r < 4; ++r) {
      float iv = __shfl(inv[mb], lr * 4 + r);
      int row = wave * WQ + mb * 16 + lr * 4 + r;
      int sq = q0 + row;
      float* op = out + (((size_t)b * SEQ + sq) * NH + h) * HD;
      #pragma unroll
      for (int nb = 0; nb < 8; ++nb)
        op[nb * 16 + lq] = acc_o[mb][nb][r] * iv;
    }
}

// ---------------- launch ----------------

extern "C" void kernel_launch(void* const* d_in, const int* in_sizes, int n_in,
                              void* d_out, int out_size, void* d_ws, size_t ws_size,
                              hipStream_t stream) {
  (void)in_sizes; (void)n_in; (void)out_size; (void)ws_size;
  const float* x    = (const float*)d_in[0];
  const float* W    = (const float*)d_in[1];
  const float* bias = (const float*)d_in[2];
  float* out = (float*)d_out;

  char* p = (char*)d_ws;
  u16* xb  = (u16*)p;  p += (size_t)MM * EMB * 2;                     // 16.8 MB
  u16* wt  = (u16*)p;  p += (size_t)N3 * EMB * 2;                     // 25.2 MB
  u16* qb  = (u16*)p;  p += (size_t)NUM_B * NH * SEQ * HD * 2;        // 16.8 MB
  u16* kb  = (u16*)p;  p += (size_t)NUM_B * NH * SEQ * HD * 2;        // 16.8 MB
  u16* vbt = (u16*)p;  p += (size_t)NUM_B * NH * HD * SEQP * 2;       // 17.0 MB
  float2* tab = (float2*)p;                                           // 2.1 MB

  k_prep<<<CVT_BLKS + TRN_BX * (EMB / 32), 256, 0, stream>>>(x, xb, tab, W, wt);
  k_gemm_qkv<<<dim3(N3 / BN, MM / BM), 512, 0, stream>>>(xb, wt, bias, tab, qb, kb, vbt);
  k_flash<<<SEQ / QT * NUM_B * NH, 512, 0, stream>>>(qb, kb, vbt, out);
}

// Round 16
// 223.430 us; speedup vs baseline: 3.6214x; 1.0061x over previous
//
#include <hip/hip_runtime.h>
#include <stdint.h>

typedef unsigned short u16;
typedef __attribute__((ext_vector_type(8))) short bf16x8;   // 8 bf16 = 4 VGPRs
typedef __attribute__((ext_vector_type(4))) float f32x4;

#define NUM_B 2
#define SEQ   2048
#define SEQP  2080      // padded V row stride
#define NH    16
#define HD    128
#define EMB   2048      // NH*HD
#define N3    6144      // 3*EMB
#define MM    4096      // NUM_B*SEQ
#define QT    256       // flash q-rows per block (8 waves)
#define WQ    32        // flash q-rows per wave
#define KT    64        // flash keys per k-tile
#define NTILE (SEQ / KT)

// ---- GEMM tile params: 128x384, BK=64, 8 waves -> 512 blocks = 2.0 exact rounds ----
#define BM 128
#define BN 384
#define BK 64
#define NT_K (EMB / BK)   // 32 K-tiles, 16 iterations of 2

__device__ __forceinline__ u16 f2bf(float f) {
  union { float f; unsigned u; } c; c.f = f;
  return (u16)((c.u + 0x7FFFu + ((c.u >> 16) & 1u)) >> 16);   // RNE
}
__device__ __forceinline__ void async16(const void* g, void* l) {
  __builtin_amdgcn_global_load_lds(
      (const __attribute__((address_space(1))) void*)g,
      (__attribute__((address_space(3))) void*)l, 16, 0, 0);
}

#define GBAR()   asm volatile("s_barrier" ::: "memory")
#define WLGKM0() asm volatile("s_waitcnt lgkmcnt(0)" ::: "memory")

// ---------------- prep: fused bf16-cast (+sincos table) and W-transpose ----------------
#define CVT_BLKS (MM * EMB / 4 / 256)          // 8192
#define TRN_BX   (N3 / 32)                     // 192
__global__ void k_prep(const float* __restrict__ x, u16* __restrict__ xb,
                       float2* __restrict__ tab,
                       const float* __restrict__ W, u16* __restrict__ Wt) {
  __shared__ float t[32][33];
  const int bid = blockIdx.x;
  if (bid < CVT_BLKS) {
    int i = bid * 256 + threadIdx.x;
    const float4 v = ((const float4*)x)[i];
    ushort4 o;
    o.x = f2bf(v.x); o.y = f2bf(v.y); o.z = f2bf(v.z); o.w = f2bf(v.w);
    ((ushort4*)xb)[i] = o;
    if (i < SEQ * HD) {
      double tt = (double)i;
      tab[i] = make_float2((float)cos(tt), (float)sin(tt));
    }
  } else {
    int b2 = bid - CVT_BLKS;
    int n0 = (b2 % TRN_BX) * 32, k0 = (b2 / TRN_BX) * 32;
    int tx = threadIdx.x & 31, ty = threadIdx.x >> 5;   // 32 x 8
    #pragma unroll
    for (int i = ty; i < 32; i += 8)
      t[i][tx] = W[(size_t)(k0 + i) * N3 + n0 + tx];
    __syncthreads();
    #pragma unroll
    for (int i = ty; i < 32; i += 8)
      Wt[(size_t)(n0 + i) * EMB + k0 + tx] = f2bf(t[tx][i]);
  }
}

// ---------------- QKV GEMM: 128x384, R4-style schedule, ZERO grid tail ----------------
// (R12-R15 best: ~131 us, MfmaUtil 32.4, no spill. UNCHANGED this round.)
__global__ __launch_bounds__(512, 2) void k_gemm_qkv(
    const u16* __restrict__ xb, const u16* __restrict__ wt,
    const float* __restrict__ bias, const float2* __restrict__ tab,
    u16* __restrict__ qb, u16* __restrict__ kb, u16* __restrict__ vbt)
{
  __shared__ __align__(16) u16 lsA[2][BM * BK];   // 16 KB x2
  __shared__ __align__(16) u16 lsB[2][BN * BK];   // 48 KB x2  (128 KB total)
  const int tid = threadIdx.x;            // 0..511
  const int wave = tid >> 6, lane = tid & 63;
  const int lq = lane & 15, lr = lane >> 4;
  const int wr = wave >> 2, wc = wave & 3;
  const int m0 = blockIdx.y * BM, n0 = blockIdx.x * BN;

  auto stA = [&](int t) {                 // whole 128x64 A tile: 2 loads/thread
    const int kt = t * BK;
    #pragma unroll
    for (int ii = 0; ii < 2; ++ii) {
      int s = ii * 512 + tid;             // 16B slot 0..1023
      int row = s >> 3, gq = (s & 7) ^ (row & 7);
      async16(xb + (size_t)(m0 + row) * EMB + kt + gq * 8, &lsA[t & 1][s * 8]);
    }
  };
  auto stB = [&](int t, int u) {          // one 128-row third: 2 loads/thread
    const int kt = t * BK;
    #pragma unroll
    for (int ii = 0; ii < 2; ++ii) {
      int s = u * 1024 + ii * 512 + tid;  // 16B slot within B tile
      int row = s >> 3, gq = (s & 7) ^ (row & 7);
      async16(wt + (size_t)(n0 + row) * EMB + kt + gq * 8, &lsB[t & 1][s * 8]);
    }
  };

  f32x4 acc[4][6];
  #pragma unroll
  for (int i = 0; i < 4; ++i)
    #pragma unroll
    for (int j = 0; j < 6; ++j)
      acc[i][j] = f32x4{0.f, 0.f, 0.f, 0.f};

  // per-lane LDS read offsets (u16 units)
  int rbase[6];
  #pragma unroll
  for (int nf = 0; nf < 6; ++nf) {
    int pg = 3 * wc + (nf >> 1);
    int col = (pg >> 2) * 128 + (pg & 3) * 16 + (nf & 1) * 64 + lq;
    rbase[nf] = col * BK;
  }
  const int aRow0 = (wr * 64 + lq) * BK;
  int qsw[2];
  qsw[0] = ((0 + lr) ^ (lq & 7)) * 8;
  qsw[1] = ((4 + lr) ^ (lq & 7)) * 8;

  // prologue: A0[2] B0[6] B1[6] = 14 loads; vmcnt(6) -> A0+B0 landed, B1 in flight
  stA(0); stB(0, 0); stB(0, 1); stB(0, 2); stB(1, 0); stB(1, 1); stB(1, 2);
  asm volatile("s_waitcnt vmcnt(6)" ::: "memory");
  GBAR();

  for (int ti = 0; ti < NT_K / 2; ++ti) {
    const int t0 = 2 * ti, t1 = t0 + 1;
    const bool nl = (ti < NT_K / 2 - 1);

    #pragma unroll
    for (int hp = 0; hp < 2; ++hp) {      // hp=0: tile t0 (buf0), hp=1: t1 (buf1)
      const u16* Ap = lsA[hp];
      const u16* Bp = lsB[hp];
      bf16x8 bfr[6][2];

      #pragma unroll
      for (int ph = 0; ph < 2; ++ph) {
        // ---- ds_read register subtile ----
        if (ph == 0) {
          #pragma unroll
          for (int nf = 0; nf < 6; ++nf)
            #pragma unroll
            for (int kk = 0; kk < 2; ++kk)
              bfr[nf][kk] = *(const bf16x8*)(Bp + rbase[nf] + qsw[kk]);
        }
        bf16x8 af[2][2];
        #pragma unroll
        for (int mfl = 0; mfl < 2; ++mfl)
          #pragma unroll
          for (int kk = 0; kk < 2; ++kk)
            af[mfl][kk] = *(const bf16x8*)(Ap + aRow0 + ((ph * 2 + mfl) * 16) * BK + qsw[kk]);

        // ---- stage schedule (R4-mirrored; hazards & vmcnt ledger in R12 notes) ----
        if (hp == 0) {
          if (ph == 0) {
            stA(t1);
          } else {
            if (nl) {
              stB(t0 + 2, 0); stB(t0 + 2, 1);
              asm volatile("s_waitcnt vmcnt(4)" ::: "memory");  // lands B(t1)+A(t1)
            } else {
              asm volatile("s_waitcnt vmcnt(0)" ::: "memory");  // drain for final tile
            }
          }
        } else {
          if (ph == 0) {
            if (nl) { stA(t0 + 2); stB(t0 + 2, 2); }
          } else {
            if (nl) {
              stB(t1 + 2, 0); stB(t1 + 2, 1); stB(t1 + 2, 2);
              asm volatile("s_waitcnt vmcnt(6)" ::: "memory");  // lands tile t0+2
            }
          }
        }
        if (ph == 0) asm volatile("s_waitcnt lgkmcnt(8)" ::: "memory");  // partial drain of 16-read phase

        GBAR();
        WLGKM0();
        __builtin_amdgcn_s_setprio(1);
        #pragma unroll
        for (int kk = 0; kk < 2; ++kk)
          #pragma unroll
          for (int mfl = 0; mfl < 2; ++mfl)
            #pragma unroll
            for (int nf = 0; nf < 6; ++nf)
              acc[ph * 2 + mfl][nf] = __builtin_amdgcn_mfma_f32_16x16x32_bf16(
                  af[mfl][kk], bfr[nf][kk], acc[ph * 2 + mfl][nf], 0, 0, 0);
        __builtin_amdgcn_s_setprio(0);
        GBAR();
      }
    }
  }

  // ---------------- epilogue (fused bias + RoPE / V-transpose, per pair-group) ----------------
  const int m0w = m0 + wr * 64;
  const int bxH = n0 >> 7;                 // = 3 * blockIdx.x
  #pragma unroll
  for (int pl = 0; pl < 3; ++pl) {
    const int pg = 3 * wc + pl;
    const int j = pg >> 2;                 // head within tile (0..2)
    const int s4 = pg & 3;                 // 16-col strip within half-head
    const int H = bxH + j;                 // absolute head index (0..47)
    const int w = H >> 4;                  // 0=q, 1=k, 2=v
    const int h = H & 15;
    const int d1 = s4 * 16 + lq;           // d within head, in [0,64); partner d1+64
    const float b1 = bias[n0 + j * 128 + d1];
    const float b2 = bias[n0 + j * 128 + d1 + 64];

    if (w == 2) {
      // V: transpose to [B,H,D,SEQP], 4 consecutive s per 8B store
      #pragma unroll
      for (int mf = 0; mf < 4; ++mf) {
        int mg0 = m0w + mf * 16 + lr * 4;
        int b = mg0 >> 11, s0 = mg0 & 2047;
        ushort4 pk;
        pk.x = f2bf(acc[mf][2 * pl][0] + b1);
        pk.y = f2bf(acc[mf][2 * pl][1] + b1);
        pk.z = f2bf(acc[mf][2 * pl][2] + b1);
        pk.w = f2bf(acc[mf][2 * pl][3] + b1);
        *(ushort4*)(vbt + ((size_t)(b * NH + h) * HD + d1) * SEQP + s0) = pk;
        pk.x = f2bf(acc[mf][2 * pl + 1][0] + b2);
        pk.y = f2bf(acc[mf][2 * pl + 1][1] + b2);
        pk.z = f2bf(acc[mf][2 * pl + 1][2] + b2);
        pk.w = f2bf(acc[mf][2 * pl + 1][3] + b2);
        *(ushort4*)(vbt + ((size_t)(b * NH + h) * HD + d1 + 64) * SEQP + s0) = pk;
      }
    } else {
      u16* basep = (w == 0) ? qb : kb;
      const float qs = (w == 0) ? 0.12751569843736827f : 1.0f;  // log2(e)/sqrt(128) into q
      #pragma unroll
      for (int mf = 0; mf < 4; ++mf)
        #pragma unroll
        for (int r = 0; r < 4; ++r) {
          int mg = m0w + mf * 16 + lr * 4 + r;
          int b = mg >> 11, s = mg & 2047;
          u16* dst = basep + ((size_t)(b * NH + h) * SEQ + s) * HD;
          float c1 = acc[mf][2 * pl][r]     + b1;
          float c2 = acc[mf][2 * pl + 1][r] + b2;
          float2 s1 = tab[s * HD + d1];
          float2 s2 = tab[s * HD + d1 + 64];
          dst[d1]      = f2bf((c1 * s1.x - c2 * s1.y) * qs);
          dst[d1 + 64] = f2bf((c2 * s2.x + c1 * s2.y) * qs);
        }
    }
  }
}

// ---------------- flash attention: QT=256, KT=64; R16 intra-tile overlap ----------------
// R16 changes (flash only): (1) setprio REMOVED — since R14 the kernel is
// 8-wave barrier-lockstep; m190 showed setprio hurts in lockstep (no wave
// role diversity; all waves raise priority together). (2) softmax/PV split
// into two key-halves: PV ks2=h consumes only lsP groups h*8..h*8+7 = exactly
// the kbi {2h, 2h+1} writes, so {exp/pack kbi 0,1 -> PV ks2=0} then
// {exp/pack kbi 2,3 -> PV ks2=1} lets half-1's trans/VALU run under half-0's
// PV MFMAs instead of sitting serially between the two MFMA clusters.
// Per-element accumulation order (ks2 0->1) and lsum order (kbi asc, qq asc)
// unchanged -> bit-identical output. Swizzles unchanged (<=2-way, R15).
__global__ __launch_bounds__(512, 1) void k_flash(
    const u16* __restrict__ qb, const u16* __restrict__ kb,
    const u16* __restrict__ vbt, float* __restrict__ out)
{
  __shared__ __align__(16) u16 lsK[2][KT * HD];   // [key][d]  16 KB x2
  __shared__ __align__(16) u16 lsV[2][HD * KT];   // [d][key]  16 KB x2
  __shared__ __align__(16) u16 lsP[8][WQ * KT];   // per-wave [qrow][key], 4 KB x8

  const int tid = threadIdx.x;            // 0..511
  const int wave = tid >> 6, lane = tid & 63;
  const int lq = lane & 15, lr = lane >> 4;
  const int i = blockIdx.x;               // 0..255
  const int xcd = i & 7, j = i >> 3;      // j: 0..31
  const int bh = xcd * 4 + (j >> 3);      // 4 heads per XCD
  const int q0 = (j & 7) * QT;
  const u16* Qg = qb + ((size_t)bh * SEQ + q0 + wave * WQ) * HD;
  const u16* Kg = kb + (size_t)bh * SEQ * HD;
  const u16* Vg = vbt + (size_t)bh * HD * SEQP;

  auto stage = [&](int tile, int buf) {
    const int k0 = tile * KT;
    #pragma unroll
    for (int ii = 0; ii < 2; ++ii) {
      int c = tid + ii * 512;             // 0..1023 (16 KB K tile)
      int key = c >> 4, grp = c & 15;
      async16(Kg + (size_t)(k0 + key) * HD + ((grp ^ (key & 7)) * 8), lsK[buf] + c * 8);
    }
    #pragma unroll
    for (int ii = 0; ii < 2; ++ii) {
      int c = tid + ii * 512;             // 0..1023 (16 KB V tile)
      int d = c >> 3, g2 = c & 7;
      async16(Vg + (size_t)d * SEQP + k0 + ((g2 ^ ((d >> 1) & 7)) * 8), lsV[buf] + c * 8);
    }
  };

  stage(0, 0);

  bf16x8 qf[2][4];
  #pragma unroll
  for (int qq = 0; qq < 2; ++qq)
    #pragma unroll
    for (int ks = 0; ks < 4; ++ks)
      qf[qq][ks] = *(const bf16x8*)(Qg + (size_t)(qq * 16 + lq) * HD + ks * 32 + lr * 8);

  f32x4 acc_o[2][8];
  float lsum[2] = {0.f, 0.f};
  #pragma unroll
  for (int mb = 0; mb < 2; ++mb)
    #pragma unroll
    for (int nb = 0; nb < 8; ++nb) acc_o[mb][nb] = f32x4{0.f, 0.f, 0.f, 0.f};

  for (int t = 0; t < NTILE; ++t) {
    const int p = t & 1;
    __syncthreads();                 // drains stage(t); all waves done with buf 1-p
    if (t + 1 < NTILE) stage(t + 1, 1 - p);

    // S^T = K Q^T : 64 keys x 32 q-rows per wave
    f32x4 sacc[4][2];
    #pragma unroll
    for (int kbi = 0; kbi < 4; ++kbi)
      #pragma unroll
      for (int qq = 0; qq < 2; ++qq) sacc[kbi][qq] = f32x4{0.f, 0.f, 0.f, 0.f};
    #pragma unroll
    for (int ks = 0; ks < 4; ++ks) {
      bf16x8 kf[4];
      #pragma unroll
      for (int kbi = 0; kbi < 4; ++kbi) {
        int key = kbi * 16 + lq;
        int g = (ks * 4 + lr) ^ (key & 7);
        kf[kbi] = *(const bf16x8*)(lsK[p] + key * HD + g * 8);
      }
      #pragma unroll
      for (int kbi = 0; kbi < 4; ++kbi)
        #pragma unroll
        for (int qq = 0; qq < 2; ++qq)
          sacc[kbi][qq] = __builtin_amdgcn_mfma_f32_16x16x32_bf16(kf[kbi], qf[qq][ks], sacc[kbi][qq], 0, 0, 0);
    }

    // softmax + PV in two key-halves (overlap exp/pack of half 1 with PV of half 0)
    #pragma unroll
    for (int half = 0; half < 2; ++half) {
      // P = exp2(S) for kbi {2*half, 2*half+1}; packed b64 writes
      #pragma unroll
      for (int kb2 = 0; kb2 < 2; ++kb2) {
        int kbi = half * 2 + kb2;
        #pragma unroll
        for (int qq = 0; qq < 2; ++qq) {
          float p0 = __builtin_amdgcn_exp2f(sacc[kbi][qq][0]);
          float p1 = __builtin_amdgcn_exp2f(sacc[kbi][qq][1]);
          float p2 = __builtin_amdgcn_exp2f(sacc[kbi][qq][2]);
          float p3 = __builtin_amdgcn_exp2f(sacc[kbi][qq][3]);
          lsum[qq] += (p0 + p1) + (p2 + p3);
          int row = qq * 16 + lq;
          int g = kbi * 4 + lr;                        // 0..15 (8B groups in 128B row)
          int gp = g ^ (row & 6) ^ ((row & 8) >> 1);
          uint2 pk;
          pk.x = (uint32_t)f2bf(p0) | ((uint32_t)f2bf(p1) << 16);
          pk.y = (uint32_t)f2bf(p2) | ((uint32_t)f2bf(p3) << 16);
          *(uint2*)(lsP[wave] + row * KT + gp * 4) = pk;
        }
      }

      // O += P V for this 32-key slot
      bf16x8 ap[2];
      #pragma unroll
      for (int mb = 0; mb < 2; ++mb) {
        int row = mb * 16 + lq;
        int sw = (row & 6) ^ ((row & 8) >> 1);
        int gb = (half * 8 + 2 * lr) ^ sw;             // even -> 16B-aligned
        ap[mb] = *(const bf16x8*)(lsP[wave] + row * KT + gb * 4);
      }
      #pragma unroll
      for (int nb = 0; nb < 8; ++nb) {
        int d = nb * 16 + lq;
        int q8 = (half * 4 + lr) ^ ((d >> 1) & 7);
        bf16x8 bv = *(const bf16x8*)(lsV[p] + d * KT + q8 * 8);
        #pragma unroll
        for (int mb = 0; mb < 2; ++mb)
          acc_o[mb][nb] = __builtin_amdgcn_mfma_f32_16x16x32_bf16(ap[mb], bv, acc_o[mb][nb], 0, 0, 0);
      }
    }
  }

  float inv[2];
  #pragma unroll
  for (int qq = 0; qq < 2; ++qq) {
    float s = lsum[qq];
    s += __shfl_xor(s, 16);
    s += __shfl_xor(s, 32);
    inv[qq] = 1.0f / s;
  }
  const int b = bh >> 4, h = bh & 15;
  #pragma unroll
  for (int mb = 0; mb < 2; ++mb)
    #pragma unroll
    for (int r = 0; r < 4; ++r) {
      float iv = __shfl(inv[mb], lr * 4 + r);
      int row = wave * WQ + mb * 16 + lr * 4 + r;
      int sq = q0 + row;
      float* op = out + (((size_t)b * SEQ + sq) * NH + h) * HD;
      #pragma unroll
      for (int nb = 0; nb < 8; ++nb)
        op[nb * 16 + lq] = acc_o[mb][nb][r] * iv;
    }
}

// ---------------- launch ----------------

extern "C" void kernel_launch(void* const* d_in, const int* in_sizes, int n_in,
                              void* d_out, int out_size, void* d_ws, size_t ws_size,
                              hipStream_t stream) {
  (void)in_sizes; (void)n_in; (void)out_size; (void)ws_size;
  const float* x    = (const float*)d_in[0];
  const float* W    = (const float*)d_in[1];
  const float* bias = (const float*)d_in[2];
  float* out = (float*)d_out;

  char* p = (char*)d_ws;
  u16* xb  = (u16*)p;  p += (size_t)MM * EMB * 2;                     // 16.8 MB
  u16* wt  = (u16*)p;  p += (size_t)N3 * EMB * 2;                     // 25.2 MB
  u16* qb  = (u16*)p;  p += (size_t)NUM_B * NH * SEQ * HD * 2;        // 16.8 MB
  u16* kb  = (u16*)p;  p += (size_t)NUM_B * NH * SEQ * HD * 2;        // 16.8 MB
  u16* vbt = (u16*)p;  p += (size_t)NUM_B * NH * HD * SEQP * 2;       // 17.0 MB
  float2* tab = (float2*)p;                                           // 2.1 MB

  k_prep<<<CVT_BLKS + TRN_BX * (EMB / 32), 256, 0, stream>>>(x, xb, tab, W, wt);
  k_gemm_qkv<<<dim3(N3 / BN, MM / BM), 512, 0, stream>>>(xb, wt, bias, tab, qb, kb, vbt);
  k_flash<<<SEQ / QT * NUM_B * NH, 512, 0, stream>>>(qb, kb, vbt, out);
}